// Round 1
// baseline (1111.842 us; speedup 1.0000x reference)
//
#include <hip/hip_runtime.h>
#include <cmath>

// ---------------------------------------------------------------------------
// Problem constants (B=8, H=W=64, C=192, 3 dilation branches of d=64, heads=64)
// ---------------------------------------------------------------------------
#define kB    8
#define kH    64
#define kW    64
#define kHW   4096          // H*W
#define kC    192
#define kD    64            // channels per dilation branch == head_dim
#define kM    (kB * kHW)    // 32768 total pixels
#define kNQKV 576           // 3*C

// ---------------------------------------------------------------------------
// Kernel 1: QKV 1x1 conv == GEMM  out[m, o] = sum_k x[m,k] * qw[o,k]
// x: (B*HW, 192) row-major.  qw: (576, 192) row-major.
// Output planar: qkv[(b*576 + o)*HW + p]
// 64x64 tile, 4x4 microtile, 256 threads. tx indexes pixels (coalesced writes).
// ---------------------------------------------------------------------------
__global__ __launch_bounds__(256) void qkv_gemm(const float* __restrict__ x,
                                                const float* __restrict__ qw,
                                                float* __restrict__ qkv) {
    __shared__ float As[64][33];   // [mm][kk]
    __shared__ float Bs[64][33];   // [nn][kk]
    const int tid = threadIdx.x;
    const int tx = tid & 15;       // pixel quad
    const int ty = tid >> 4;       // out-channel quad
    const int m0 = blockIdx.x * 64;
    const int n0 = blockIdx.y * 64;

    float acc[4][4];
#pragma unroll
    for (int r = 0; r < 4; ++r)
#pragma unroll
        for (int j = 0; j < 4; ++j) acc[r][j] = 0.f;

    for (int k0 = 0; k0 < kC; k0 += 32) {
#pragma unroll
        for (int it = 0; it < 8; ++it) {
            int l = it * 256 + tid;
            int mm = l >> 5, kk = l & 31;
            As[mm][kk] = x[(size_t)(m0 + mm) * kC + k0 + kk];
            Bs[mm][kk] = qw[(size_t)(n0 + mm) * kC + k0 + kk];
        }
        __syncthreads();
#pragma unroll
        for (int kk = 0; kk < 32; ++kk) {
            float a[4], b[4];
#pragma unroll
            for (int r = 0; r < 4; ++r) a[r] = As[tx * 4 + r][kk];
#pragma unroll
            for (int j = 0; j < 4; ++j) b[j] = Bs[ty * 4 + j][kk];
#pragma unroll
            for (int r = 0; r < 4; ++r)
#pragma unroll
                for (int j = 0; j < 4; ++j) acc[r][j] += a[r] * b[j];
        }
        __syncthreads();
    }
    const int m_base = m0 + tx * 4;
    const int b = m_base >> 12;
    const int p = m_base & 4095;
#pragma unroll
    for (int j = 0; j < 4; ++j) {
        int n = n0 + ty * 4 + j;
        float4 v = make_float4(acc[0][j], acc[1][j], acc[2][j], acc[3][j]);
        *(float4*)&qkv[(size_t)(b * kNQKV + n) * kHW + p] = v;
    }
}

// ---------------------------------------------------------------------------
// Tiny transpose of deform weights: dw (o,c,kk) -> dwt (kk,c,o)
// ---------------------------------------------------------------------------
__global__ void dw_transpose(const float* __restrict__ dw, float* __restrict__ dwt) {
    int l = blockIdx.x * 256 + threadIdx.x;   // 64*64*9 = 36864
    if (l >= kD * kD * 9) return;
    int o = l / (kD * 9);
    int c = (l / 9) % kD;
    int kk = l % 9;
    dwt[(kk * kD + c) * kD + o] = dw[l];
}

// ---------------------------------------------------------------------------
// Kernel 2: offsets conv: 3x3 dilated conv, 64 -> 18 channels, padding = dil
// input: k plane of qkv (branch), output planar off[(b*18 + j)*HW + p]
// one thread per output pixel; block = (b, j, 256-pixel tile)
// ---------------------------------------------------------------------------
__global__ __launch_bounds__(256) void off_conv(const float* __restrict__ qkv,
                                                const float* __restrict__ ow,
                                                const float* __restrict__ ob,
                                                float* __restrict__ offb,
                                                int branch, int dil) {
    __shared__ float wsm[64 * 9];
    const int lb = blockIdx.x;
    const int pt = lb & 15;
    const int j = (lb >> 4) % 18;
    const int b = lb / (16 * 18);
    const int tid = threadIdx.x;
    for (int l = tid; l < 64 * 9; l += 256) wsm[l] = ow[j * 64 * 9 + l];
    __syncthreads();

    const int p = pt * 256 + tid;
    const int y = p >> 6, x = p & 63;
    const float* kin = qkv + ((size_t)b * kNQKV + kC + branch * kD) * kHW;
    float acc = ob[j];
    for (int c = 0; c < kD; ++c) {
        const float* pl = kin + (size_t)c * kHW;
#pragma unroll
        for (int ky = 0; ky < 3; ++ky) {
            int yy = y + (ky - 1) * dil;
#pragma unroll
            for (int kx = 0; kx < 3; ++kx) {
                int xx = x + (kx - 1) * dil;
                float v = 0.f;
                if (yy >= 0 && yy < kH && xx >= 0 && xx < kW) v = pl[yy * kW + xx];
                acc += v * wsm[c * 9 + ky * 3 + kx];
            }
        }
    }
    offb[((size_t)b * 18 + j) * kHW + p] = acc;
}

// ---------------------------------------------------------------------------
// Kernel 3: deformable 3x3 conv (64 -> 64 ch).  One block per (b, row y).
// Per tap kk: stage per-pixel bilinear corner idx/weights, sample all 64
// channels into LDS (64ch x 64px), accumulate 64x64 output tile with the
// tap's 64x64 weight slice (dwt pre-transposed to [kk][c][o]).
// ---------------------------------------------------------------------------
__global__ __launch_bounds__(256) void deform_conv(const float* __restrict__ inbase,
                                                   const float* __restrict__ offb,
                                                   const float* __restrict__ dwt,
                                                   const float* __restrict__ db,
                                                   float* __restrict__ outp,
                                                   int bstride, int dil) {
    __shared__ float smp[64][64];   // [c][x]
    __shared__ float wkt[64][64];   // [c][o]
    __shared__ int   sid[4][64];
    __shared__ float swt[4][64];

    const int b = blockIdx.x >> 6;
    const int y = blockIdx.x & 63;
    const int tid = threadIdx.x;
    const int tx = tid & 15;   // pixel quad (x = tx*4 + r)
    const int ty = tid >> 4;   // out-channel quad (o = ty*4 + j)

    float acc[4][4];
#pragma unroll
    for (int r = 0; r < 4; ++r)
#pragma unroll
        for (int j = 0; j < 4; ++j) acc[r][j] = 0.f;

    const float* inb = inbase + (size_t)b * bstride;

    for (int kk = 0; kk < 9; ++kk) {
        const int ky = kk / 3, kx = kk % 3;
        if (tid < 64) {
            const int x = tid;
            float oy = offb[((size_t)b * 18 + kk * 2 + 0) * kHW + y * kW + x];
            float ox = offb[((size_t)b * 18 + kk * 2 + 1) * kHW + y * kW + x];
            float py = (float)y + (float)((ky - 1) * dil) + oy;
            float px = (float)x + (float)((kx - 1) * dil) + ox;
            float fy = floorf(py), fx = floorf(px);
            float wy = py - fy, wx = px - fx;
            int y0 = (int)fy, x0 = (int)fx;
            int y1 = y0 + 1, x1 = x0 + 1;
            int y0c = min(max(y0, 0), kH - 1), x0c = min(max(x0, 0), kW - 1);
            int y1c = min(max(y1, 0), kH - 1), x1c = min(max(x1, 0), kW - 1);
            bool vy0 = (y0 >= 0) & (y0 < kH), vx0 = (x0 >= 0) & (x0 < kW);
            bool vy1 = (y1 >= 0) & (y1 < kH), vx1 = (x1 >= 0) & (x1 < kW);
            sid[0][x] = y0c * kW + x0c; swt[0][x] = (vy0 && vx0) ? (1.f - wy) * (1.f - wx) : 0.f;
            sid[1][x] = y0c * kW + x1c; swt[1][x] = (vy0 && vx1) ? (1.f - wy) * wx : 0.f;
            sid[2][x] = y1c * kW + x0c; swt[2][x] = (vy1 && vx0) ? wy * (1.f - wx) : 0.f;
            sid[3][x] = y1c * kW + x1c; swt[3][x] = (vy1 && vx1) ? wy * wx : 0.f;
        }
        __syncthreads();
        // stage this tap's weight slice: wkt[c][o] = dwt[kk][c][o]
#pragma unroll
        for (int it = 0; it < 16; ++it) {
            int l = it * 256 + tid;
            int c = l >> 6, o = l & 63;
            wkt[c][o] = dwt[((size_t)kk * kD + c) * kD + o];
        }
        // bilinear sample all 64 channels for this row
        {
            const int x = tid & 63;
            const int cg = tid >> 6;   // 0..3
            const int i00 = sid[0][x], i01 = sid[1][x], i10 = sid[2][x], i11 = sid[3][x];
            const float w00 = swt[0][x], w01 = swt[1][x], w10 = swt[2][x], w11 = swt[3][x];
#pragma unroll
            for (int cc = 0; cc < 16; ++cc) {
                int c = cg * 16 + cc;
                const float* pl = inb + (size_t)c * kHW;
                smp[c][x] = w00 * pl[i00] + w01 * pl[i01] + w10 * pl[i10] + w11 * pl[i11];
            }
        }
        __syncthreads();
        // accumulate: acc[px_r][o_j] += smp[c][px] * wkt[c][o]
        for (int c = 0; c < kD; ++c) {
            float4 a = *(const float4*)&smp[c][tx * 4];
            float4 w = *(const float4*)&wkt[c][ty * 4];
            acc[0][0] += a.x * w.x; acc[0][1] += a.x * w.y; acc[0][2] += a.x * w.z; acc[0][3] += a.x * w.w;
            acc[1][0] += a.y * w.x; acc[1][1] += a.y * w.y; acc[1][2] += a.y * w.z; acc[1][3] += a.y * w.w;
            acc[2][0] += a.z * w.x; acc[2][1] += a.z * w.y; acc[2][2] += a.z * w.z; acc[2][3] += a.z * w.w;
            acc[3][0] += a.w * w.x; acc[3][1] += a.w * w.y; acc[3][2] += a.w * w.z; acc[3][3] += a.w * w.w;
        }
        __syncthreads();
    }
#pragma unroll
    for (int j = 0; j < 4; ++j) {
        int o = ty * 4 + j;
        float bias = db[o];
        float4 v = make_float4(acc[0][j] + bias, acc[1][j] + bias, acc[2][j] + bias, acc[3][j] + bias);
        *(float4*)&outp[((size_t)b * kD + o) * kHW + y * kW + tx * 4] = v;
    }
}

// ---------------------------------------------------------------------------
// Kernel 4: 9-tap local attention for one dilation branch.
// One thread per pixel (64-thread blocks = one image row).
// Zero-padded taps (unfold3 semantics): score contribution 0, value 0 — they
// DO participate in softmax with exp(0 - max) weight. Replicated via mask-mul.
// Output planar: ao[(branch*64 + c) * M + global_pixel]
// ---------------------------------------------------------------------------
__global__ __launch_bounds__(64) void attn_kernel(const float* __restrict__ qkv,
                                                  const float* __restrict__ ksrc,
                                                  const float* __restrict__ vsrc,
                                                  float* __restrict__ ao,
                                                  int branch, int dil, int kvstride) {
    const int pg = blockIdx.x * 64 + threadIdx.x;
    const int b = pg >> 12;
    const int p = pg & 4095;
    const int y = p >> 6, x = p & 63;
    const float* qb = qkv + ((size_t)b * kNQKV + branch * kD) * kHW + p;
    const float* kb = ksrc + (size_t)b * kvstride;
    const float* vb = vsrc + (size_t)b * kvstride;

    int offs[9]; float msk[9];
#pragma unroll
    for (int kk = 0; kk < 9; ++kk) {
        int dy = (kk / 3 - 1) * dil, dx = (kk % 3 - 1) * dil;
        int yy = y + dy, xx = x + dx;
        bool v = (yy >= 0) & (yy < kH) & (xx >= 0) & (xx < kW);
        offs[kk] = v ? (p + dy * kW + dx) : 0;
        msk[kk] = v ? 1.f : 0.f;
    }
    float sc[9];
#pragma unroll
    for (int kk = 0; kk < 9; ++kk) sc[kk] = 0.f;
    for (int c = 0; c < kD; ++c) {
        float qv = qb[(size_t)c * kHW];
        const float* kp = kb + (size_t)c * kHW;
#pragma unroll
        for (int kk = 0; kk < 9; ++kk) sc[kk] += qv * (msk[kk] * kp[offs[kk]]);
    }
    float mx = -1e30f;
#pragma unroll
    for (int kk = 0; kk < 9; ++kk) { sc[kk] *= 0.125f; mx = fmaxf(mx, sc[kk]); }
    float e[9], s = 0.f;
#pragma unroll
    for (int kk = 0; kk < 9; ++kk) { e[kk] = __expf(sc[kk] - mx); s += e[kk]; }
    float inv = 1.f / s;
#pragma unroll
    for (int kk = 0; kk < 9; ++kk) e[kk] *= inv;

    for (int c = 0; c < kD; ++c) {
        const float* vp = vb + (size_t)c * kHW;
        float o = 0.f;
#pragma unroll
        for (int kk = 0; kk < 9; ++kk) o += e[kk] * (msk[kk] * vp[offs[kk]]);
        ao[(size_t)(branch * kD + c) * kM + pg] = o;
    }
}

// ---------------------------------------------------------------------------
// Kernel 5: output projection GEMM.  ao: (192, M) planar; pw: (192n, 192k);
// out[m*192 + n] = sum_k ao[k][m]*pw[n][k] + pb[n]
// ---------------------------------------------------------------------------
__global__ __launch_bounds__(256) void proj_gemm(const float* __restrict__ ao,
                                                 const float* __restrict__ pw,
                                                 const float* __restrict__ pb,
                                                 float* __restrict__ out) {
    __shared__ float As[32][64];   // [kk][mm]
    __shared__ float Bs[64][33];   // [nn][kk]
    const int tid = threadIdx.x;
    const int tx = tid & 15;   // n quad (coalesced writes along n)
    const int ty = tid >> 4;   // m quad
    const int m0 = blockIdx.x * 64;
    const int n0 = blockIdx.y * 64;

    float acc[4][4];   // [m r][n j]
#pragma unroll
    for (int r = 0; r < 4; ++r)
#pragma unroll
        for (int j = 0; j < 4; ++j) acc[r][j] = 0.f;

    for (int k0 = 0; k0 < kC; k0 += 32) {
#pragma unroll
        for (int it = 0; it < 8; ++it) {
            int l = it * 256 + tid;
            int kk = l >> 6, mm = l & 63;
            As[kk][mm] = ao[(size_t)(k0 + kk) * kM + m0 + mm];
        }
#pragma unroll
        for (int it = 0; it < 8; ++it) {
            int l = it * 256 + tid;
            int nn = l >> 5, kk = l & 31;
            Bs[nn][kk] = pw[(size_t)(n0 + nn) * kC + k0 + kk];
        }
        __syncthreads();
#pragma unroll
        for (int kk = 0; kk < 32; ++kk) {
            float a[4], b[4];
#pragma unroll
            for (int r = 0; r < 4; ++r) a[r] = As[kk][ty * 4 + r];
#pragma unroll
            for (int j = 0; j < 4; ++j) b[j] = Bs[tx * 4 + j][kk];
#pragma unroll
            for (int r = 0; r < 4; ++r)
#pragma unroll
                for (int j = 0; j < 4; ++j) acc[r][j] += a[r] * b[j];
        }
        __syncthreads();
    }
#pragma unroll
    for (int r = 0; r < 4; ++r) {
        int m = m0 + ty * 4 + r;
        float4 v;
        v.x = acc[r][0] + pb[n0 + tx * 4 + 0];
        v.y = acc[r][1] + pb[n0 + tx * 4 + 1];
        v.z = acc[r][2] + pb[n0 + tx * 4 + 2];
        v.w = acc[r][3] + pb[n0 + tx * 4 + 3];
        *(float4*)&out[(size_t)m * kC + n0 + tx * 4] = v;
    }
}

// ---------------------------------------------------------------------------
// Host launcher
// ---------------------------------------------------------------------------
extern "C" void kernel_launch(void* const* d_in, const int* in_sizes, int n_in,
                              void* d_out, int out_size, void* d_ws, size_t ws_size,
                              hipStream_t stream) {
    const float* x      = (const float*)d_in[0];
    const float* qkv_w  = (const float*)d_in[1];
    const float* proj_w = (const float*)d_in[2];
    const float* proj_b = (const float*)d_in[3];
    const float* off_w2 = (const float*)d_in[4];
    const float* off_b2 = (const float*)d_in[5];
    const float* def_w2 = (const float*)d_in[6];
    const float* def_b2 = (const float*)d_in[7];
    const float* off_w3 = (const float*)d_in[8];
    const float* off_b3 = (const float*)d_in[9];
    const float* def_w3 = (const float*)d_in[10];
    const float* def_b3 = (const float*)d_in[11];
    float* out = (float*)d_out;

    // workspace layout (floats); buffers reused across branches (stream order)
    float* ws   = (float*)d_ws;
    float* qkv  = ws;                               // 576 * M
    float* offb = qkv + (size_t)kNQKV * kM;         // 18 * M
    float* kd   = offb + (size_t)18 * kM;           // 64 * M
    float* vd   = kd + (size_t)kD * kM;             // 64 * M
    float* ao   = vd + (size_t)kD * kM;             // 192 * M
    float* dwt2 = ao + (size_t)kC * kM;             // 36864
    float* dwt3 = dwt2 + kD * kD * 9;               // 36864

    // 1. QKV projection
    qkv_gemm<<<dim3(kM / 64, kNQKV / 64), 256, 0, stream>>>(x, qkv_w, qkv);

    // weight transposes (independent of qkv)
    dw_transpose<<<144, 256, 0, stream>>>(def_w2, dwt2);
    dw_transpose<<<144, 256, 0, stream>>>(def_w3, dwt3);

    // 2. branch 0 (dil=1): attention on original k/v
    attn_kernel<<<kM / 64, 64, 0, stream>>>(
        qkv, qkv + (size_t)kC * kHW, qkv + (size_t)2 * kC * kHW, ao,
        0, 1, kNQKV * kHW);

    // 3. branch 1 (dil=2)
    off_conv<<<kB * 18 * 16, 256, 0, stream>>>(qkv, off_w2, off_b2, offb, 1, 2);
    deform_conv<<<kB * kH, 256, 0, stream>>>(
        qkv + (size_t)(kC + 1 * kD) * kHW, offb, dwt2, def_b2, kd, kNQKV * kHW, 2);
    deform_conv<<<kB * kH, 256, 0, stream>>>(
        qkv + (size_t)(2 * kC + 1 * kD) * kHW, offb, dwt2, def_b2, vd, kNQKV * kHW, 2);
    attn_kernel<<<kM / 64, 64, 0, stream>>>(qkv, kd, vd, ao, 1, 2, kD * kHW);

    // 4. branch 2 (dil=3)
    off_conv<<<kB * 18 * 16, 256, 0, stream>>>(qkv, off_w3, off_b3, offb, 2, 3);
    deform_conv<<<kB * kH, 256, 0, stream>>>(
        qkv + (size_t)(kC + 2 * kD) * kHW, offb, dwt3, def_b3, kd, kNQKV * kHW, 3);
    deform_conv<<<kB * kH, 256, 0, stream>>>(
        qkv + (size_t)(2 * kC + 2 * kD) * kHW, offb, dwt3, def_b3, vd, kNQKV * kHW, 3);
    attn_kernel<<<kM / 64, 64, 0, stream>>>(qkv, kd, vd, ao, 2, 3, kD * kHW);

    // 5. output projection
    proj_gemm<<<dim3(kM / 64, kC / 64), 256, 0, stream>>>(ao, proj_w, proj_b, out);
}

// Round 2
// 1041.044 us; speedup vs baseline: 1.0680x; 1.0680x over previous
//
#include <hip/hip_runtime.h>
#include <cmath>

// ---------------------------------------------------------------------------
// Problem constants (B=8, H=W=64, C=192, 3 dilation branches of d=64, heads=64)
// ---------------------------------------------------------------------------
#define kB    8
#define kH    64
#define kW    64
#define kHW   4096          // H*W
#define kC    192
#define kD    64            // channels per dilation branch == head_dim
#define kM    (kB * kHW)    // 32768 total pixels
#define kNQKV 576           // 3*C

// ---------------------------------------------------------------------------
// Kernel 1: QKV 1x1 conv == GEMM  out[m, o] = sum_k x[m,k] * qw[o,k]
// x: (B*HW, 192) row-major.  qw: (576, 192) row-major.
// Output planar: qkv[(b*576 + o)*HW + p]
// 128(m)x64(n) tile, 256 threads, 8x4 microtile (m split 4+4 so the
// ds_read_b128 fragment reads are 2-way bank-aliased = free).
// LDS stored transposed [kk][mm] to enable float4 fragment reads.
// ---------------------------------------------------------------------------
__global__ __launch_bounds__(256) void qkv_gemm(const float* __restrict__ x,
                                                const float* __restrict__ qw,
                                                float* __restrict__ qkv) {
    __shared__ float As[32][132];   // [kk][mm], pad 4 keeps float4 alignment
    __shared__ float Bs[32][68];    // [kk][nn]
    const int tid = threadIdx.x;
    const int tx = tid & 15;        // m quad within half-tile
    const int ty = tid >> 4;        // n quad
    const int m0 = blockIdx.x * 128;
    const int n0 = blockIdx.y * 64;

    float accA[4][4], accB[4][4];
#pragma unroll
    for (int r = 0; r < 4; ++r)
#pragma unroll
        for (int j = 0; j < 4; ++j) { accA[r][j] = 0.f; accB[r][j] = 0.f; }

    for (int k0 = 0; k0 < kC; k0 += 32) {
#pragma unroll
        for (int it = 0; it < 16; ++it) {
            int l = it * 256 + tid;
            int kk = l & 31, mm = l >> 5;
            As[kk][mm] = x[(size_t)(m0 + mm) * kC + k0 + kk];
        }
#pragma unroll
        for (int it = 0; it < 8; ++it) {
            int l = it * 256 + tid;
            int kk = l & 31, nn = l >> 5;
            Bs[kk][nn] = qw[(size_t)(n0 + nn) * kC + k0 + kk];
        }
        __syncthreads();
#pragma unroll
        for (int kk = 0; kk < 32; ++kk) {
            float4 a0 = *(const float4*)&As[kk][tx * 4];
            float4 a1 = *(const float4*)&As[kk][64 + tx * 4];
            float4 b  = *(const float4*)&Bs[kk][ty * 4];
            const float ar0[4] = {a0.x, a0.y, a0.z, a0.w};
            const float ar1[4] = {a1.x, a1.y, a1.z, a1.w};
            const float br[4]  = {b.x, b.y, b.z, b.w};
#pragma unroll
            for (int r = 0; r < 4; ++r)
#pragma unroll
                for (int j = 0; j < 4; ++j) {
                    accA[r][j] += ar0[r] * br[j];
                    accB[r][j] += ar1[r] * br[j];
                }
        }
        __syncthreads();
    }
    const int b_img = m0 >> 12;
    const int p = (m0 & 4095) + tx * 4;
#pragma unroll
    for (int j = 0; j < 4; ++j) {
        int n = n0 + ty * 4 + j;
        float* dst = &qkv[(size_t)(b_img * kNQKV + n) * kHW + p];
        *(float4*)dst = make_float4(accA[0][j], accA[1][j], accA[2][j], accA[3][j]);
        *(float4*)(dst + 64) = make_float4(accB[0][j], accB[1][j], accB[2][j], accB[3][j]);
    }
}

// ---------------------------------------------------------------------------
// Tiny transpose of deform weights: dw (o,c,kk) -> dwt (kk,c,o)
// ---------------------------------------------------------------------------
__global__ void dw_transpose(const float* __restrict__ dw, float* __restrict__ dwt) {
    int l = blockIdx.x * 256 + threadIdx.x;   // 64*64*9 = 36864
    if (l >= kD * kD * 9) return;
    int o = l / (kD * 9);
    int c = (l / 9) % kD;
    int kk = l % 9;
    dwt[(kk * kD + c) * kD + o] = dw[l];
}

// ---------------------------------------------------------------------------
// Kernel 2: offsets conv: 3x3 dilated conv, 64 -> 18 channels, padding = dil
// ---------------------------------------------------------------------------
__global__ __launch_bounds__(256) void off_conv(const float* __restrict__ qkv,
                                                const float* __restrict__ ow,
                                                const float* __restrict__ ob,
                                                float* __restrict__ offb,
                                                int branch, int dil) {
    __shared__ float wsm[64 * 9];
    const int lb = blockIdx.x;
    const int pt = lb & 15;
    const int j = (lb >> 4) % 18;
    const int b = lb / (16 * 18);
    const int tid = threadIdx.x;
    for (int l = tid; l < 64 * 9; l += 256) wsm[l] = ow[j * 64 * 9 + l];
    __syncthreads();

    const int p = pt * 256 + tid;
    const int y = p >> 6, x = p & 63;
    const float* kin = qkv + ((size_t)b * kNQKV + kC + branch * kD) * kHW;
    float acc = ob[j];
    for (int c = 0; c < kD; ++c) {
        const float* pl = kin + (size_t)c * kHW;
#pragma unroll
        for (int ky = 0; ky < 3; ++ky) {
            int yy = y + (ky - 1) * dil;
#pragma unroll
            for (int kx = 0; kx < 3; ++kx) {
                int xx = x + (kx - 1) * dil;
                float v = 0.f;
                if (yy >= 0 && yy < kH && xx >= 0 && xx < kW) v = pl[yy * kW + xx];
                acc += v * wsm[c * 9 + ky * 3 + kx];
            }
        }
    }
    offb[((size_t)b * 18 + j) * kHW + p] = acc;
}

// ---------------------------------------------------------------------------
// Kernel 3: FUSED deformable 3x3 conv for k AND v (they share offsets and
// weights). One block per (b, row y). Per tap: stage bilinear idx/weights +
// the tap's 64x64 weight slice, sample both k and v rows into LDS, then a
// 64px x 64out outer-product accumulation for both.
// ---------------------------------------------------------------------------
__global__ __launch_bounds__(256) void deform_conv2(const float* __restrict__ inkbase,
                                                    const float* __restrict__ invbase,
                                                    const float* __restrict__ offb,
                                                    const float* __restrict__ dwt,
                                                    const float* __restrict__ db,
                                                    float* __restrict__ outk,
                                                    float* __restrict__ outv,
                                                    int bstride, int dil) {
    __shared__ float smpk[64][64];  // [c][x]
    __shared__ float smpv[64][64];  // [c][x]
    __shared__ float wkt[64][64];   // [c][o]
    __shared__ int   sid[4][64];
    __shared__ float swt[4][64];

    const int b = blockIdx.x >> 6;
    const int y = blockIdx.x & 63;
    const int tid = threadIdx.x;
    const int tx = tid & 15;   // pixel quad (x = tx*4 + r)
    const int ty = tid >> 4;   // out-channel quad (o = ty*4 + j)

    float accK[4][4], accV[4][4];
#pragma unroll
    for (int r = 0; r < 4; ++r)
#pragma unroll
        for (int j = 0; j < 4; ++j) { accK[r][j] = 0.f; accV[r][j] = 0.f; }

    const float* inK = inkbase + (size_t)b * bstride;
    const float* inV = invbase + (size_t)b * bstride;

    for (int kk = 0; kk < 9; ++kk) {
        const int ky = kk / 3, kx = kk % 3;
        if (tid < 64) {
            const int x = tid;
            float oy = offb[((size_t)b * 18 + kk * 2 + 0) * kHW + y * kW + x];
            float ox = offb[((size_t)b * 18 + kk * 2 + 1) * kHW + y * kW + x];
            float py = (float)y + (float)((ky - 1) * dil) + oy;
            float px = (float)x + (float)((kx - 1) * dil) + ox;
            float fy = floorf(py), fx = floorf(px);
            float wy = py - fy, wx = px - fx;
            int y0 = (int)fy, x0 = (int)fx;
            int y1 = y0 + 1, x1 = x0 + 1;
            int y0c = min(max(y0, 0), kH - 1), x0c = min(max(x0, 0), kW - 1);
            int y1c = min(max(y1, 0), kH - 1), x1c = min(max(x1, 0), kW - 1);
            bool vy0 = (y0 >= 0) & (y0 < kH), vx0 = (x0 >= 0) & (x0 < kW);
            bool vy1 = (y1 >= 0) & (y1 < kH), vx1 = (x1 >= 0) & (x1 < kW);
            sid[0][x] = y0c * kW + x0c; swt[0][x] = (vy0 && vx0) ? (1.f - wy) * (1.f - wx) : 0.f;
            sid[1][x] = y0c * kW + x1c; swt[1][x] = (vy0 && vx1) ? (1.f - wy) * wx : 0.f;
            sid[2][x] = y1c * kW + x0c; swt[2][x] = (vy1 && vx0) ? wy * (1.f - wx) : 0.f;
            sid[3][x] = y1c * kW + x1c; swt[3][x] = (vy1 && vx1) ? wy * wx : 0.f;
        }
#pragma unroll
        for (int it = 0; it < 16; ++it) {
            int l = it * 256 + tid;
            int c = l >> 6, o = l & 63;
            wkt[c][o] = dwt[((size_t)kk * kD + c) * kD + o];
        }
        __syncthreads();
        {
            const int x = tid & 63;
            const int cg = tid >> 6;   // 0..3
            const int i00 = sid[0][x], i01 = sid[1][x], i10 = sid[2][x], i11 = sid[3][x];
            const float w00 = swt[0][x], w01 = swt[1][x], w10 = swt[2][x], w11 = swt[3][x];
#pragma unroll
            for (int cc = 0; cc < 16; ++cc) {
                int c = cg * 16 + cc;
                const float* pk = inK + (size_t)c * kHW;
                const float* pv = inV + (size_t)c * kHW;
                smpk[c][x] = w00 * pk[i00] + w01 * pk[i01] + w10 * pk[i10] + w11 * pk[i11];
                smpv[c][x] = w00 * pv[i00] + w01 * pv[i01] + w10 * pv[i10] + w11 * pv[i11];
            }
        }
        __syncthreads();
        for (int c = 0; c < kD; ++c) {
            float4 ak = *(const float4*)&smpk[c][tx * 4];
            float4 av = *(const float4*)&smpv[c][tx * 4];
            float4 w  = *(const float4*)&wkt[c][ty * 4];
            const float akr[4] = {ak.x, ak.y, ak.z, ak.w};
            const float avr[4] = {av.x, av.y, av.z, av.w};
            const float wr[4]  = {w.x, w.y, w.z, w.w};
#pragma unroll
            for (int r = 0; r < 4; ++r)
#pragma unroll
                for (int j = 0; j < 4; ++j) {
                    accK[r][j] += akr[r] * wr[j];
                    accV[r][j] += avr[r] * wr[j];
                }
        }
        __syncthreads();
    }
#pragma unroll
    for (int j = 0; j < 4; ++j) {
        int o = ty * 4 + j;
        float bias = db[o];
        float4 vk = make_float4(accK[0][j] + bias, accK[1][j] + bias, accK[2][j] + bias, accK[3][j] + bias);
        float4 vv = make_float4(accV[0][j] + bias, accV[1][j] + bias, accV[2][j] + bias, accV[3][j] + bias);
        *(float4*)&outk[((size_t)b * kD + o) * kHW + y * kW + tx * 4] = vk;
        *(float4*)&outv[((size_t)b * kD + o) * kHW + y * kW + tx * 4] = vv;
    }
}

// ---------------------------------------------------------------------------
// Kernel 4: 9-tap local attention, one block per (b, row).
// 512 threads = 64 px * 8 channel-groups (8 channels each).
// Partial QK scores per group -> LDS reduce -> softmax (replicated) -> PV.
// Zero-padded taps keep score exactly 0 and participate in softmax (matches
// unfold3 zero-padding semantics).
// ---------------------------------------------------------------------------
__global__ __launch_bounds__(512) void attn_kernel(const float* __restrict__ qkv,
                                                   const float* __restrict__ ksrc,
                                                   const float* __restrict__ vsrc,
                                                   float* __restrict__ ao,
                                                   int branch, int dil, int kvstride) {
    __shared__ float part[9][8][64];
    const int tid = threadIdx.x;
    const int x = tid & 63;
    const int g = tid >> 6;          // 0..7, wave-uniform
    const int b = blockIdx.x >> 6;
    const int y = blockIdx.x & 63;
    const int p = y * kW + x;
    const int pg = b * kHW + p;

    const float* qb = qkv + ((size_t)b * kNQKV + branch * kD) * kHW + p;
    const float* kb = ksrc + (size_t)b * kvstride;
    const float* vb = vsrc + (size_t)b * kvstride;

    int offs[9]; float msk[9];
#pragma unroll
    for (int kk = 0; kk < 9; ++kk) {
        int dy = (kk / 3 - 1) * dil, dx = (kk % 3 - 1) * dil;
        int yy = y + dy, xx = x + dx;
        bool v = (yy >= 0) & (yy < kH) & (xx >= 0) & (xx < kW);
        offs[kk] = v ? (p + dy * kW + dx) : 0;
        msk[kk] = v ? 1.f : 0.f;
    }
    float sc[9];
#pragma unroll
    for (int kk = 0; kk < 9; ++kk) sc[kk] = 0.f;
#pragma unroll
    for (int cc = 0; cc < 8; ++cc) {
        int c = g * 8 + cc;
        float qv = qb[(size_t)c * kHW];
        const float* kp = kb + (size_t)c * kHW;
#pragma unroll
        for (int kk = 0; kk < 9; ++kk) sc[kk] += qv * (msk[kk] * kp[offs[kk]]);
    }
#pragma unroll
    for (int kk = 0; kk < 9; ++kk) part[kk][g][x] = sc[kk];
    __syncthreads();

    float e[9], mx = -1e30f;
#pragma unroll
    for (int kk = 0; kk < 9; ++kk) {
        float s = 0.f;
#pragma unroll
        for (int gg = 0; gg < 8; ++gg) s += part[kk][gg][x];
        s *= 0.125f;
        e[kk] = s;
        mx = fmaxf(mx, s);
    }
    float ssum = 0.f;
#pragma unroll
    for (int kk = 0; kk < 9; ++kk) { e[kk] = __expf(e[kk] - mx); ssum += e[kk]; }
    float inv = 1.f / ssum;
#pragma unroll
    for (int kk = 0; kk < 9; ++kk) e[kk] = e[kk] * inv * msk[kk];

#pragma unroll
    for (int cc = 0; cc < 8; ++cc) {
        int c = g * 8 + cc;
        const float* vp = vb + (size_t)c * kHW;
        float o = 0.f;
#pragma unroll
        for (int kk = 0; kk < 9; ++kk) o += e[kk] * vp[offs[kk]];
        ao[(size_t)(branch * kD + c) * kM + pg] = o;
    }
}

// ---------------------------------------------------------------------------
// Kernel 5: output projection GEMM.  ao: (192, M) planar; pw: (192n, 192k);
// out[m*192 + n] = sum_k ao[k][m]*pw[n][k] + pb[n]
// 128(m)x64(n) tile, same microtile structure as qkv_gemm. A-tile loads
// straight from planar ao (no transpose => conflict-free LDS writes).
// ---------------------------------------------------------------------------
__global__ __launch_bounds__(256) void proj_gemm(const float* __restrict__ ao,
                                                 const float* __restrict__ pw,
                                                 const float* __restrict__ pb,
                                                 float* __restrict__ out) {
    __shared__ float As[32][132];   // [kk][mm]
    __shared__ float Bs[32][68];    // [kk][nn]
    const int tid = threadIdx.x;
    const int tx = tid & 15;   // m quad
    const int ty = tid >> 4;   // n quad
    const int m0 = blockIdx.x * 128;
    const int n0 = blockIdx.y * 64;

    float accA[4][4], accB[4][4];
#pragma unroll
    for (int r = 0; r < 4; ++r)
#pragma unroll
        for (int j = 0; j < 4; ++j) { accA[r][j] = 0.f; accB[r][j] = 0.f; }

    for (int k0 = 0; k0 < kC; k0 += 32) {
#pragma unroll
        for (int it = 0; it < 16; ++it) {
            int l = it * 256 + tid;
            int mm = l & 127, kk = l >> 7;
            As[kk][mm] = ao[(size_t)(k0 + kk) * kM + m0 + mm];
        }
#pragma unroll
        for (int it = 0; it < 8; ++it) {
            int l = it * 256 + tid;
            int kk = l & 31, nn = l >> 5;
            Bs[kk][nn] = pw[(size_t)(n0 + nn) * kC + k0 + kk];
        }
        __syncthreads();
#pragma unroll
        for (int kk = 0; kk < 32; ++kk) {
            float4 a0 = *(const float4*)&As[kk][tx * 4];
            float4 a1 = *(const float4*)&As[kk][64 + tx * 4];
            float4 b  = *(const float4*)&Bs[kk][ty * 4];
            const float ar0[4] = {a0.x, a0.y, a0.z, a0.w};
            const float ar1[4] = {a1.x, a1.y, a1.z, a1.w};
            const float br[4]  = {b.x, b.y, b.z, b.w};
#pragma unroll
            for (int r = 0; r < 4; ++r)
#pragma unroll
                for (int j = 0; j < 4; ++j) {
                    accA[r][j] += ar0[r] * br[j];
                    accB[r][j] += ar1[r] * br[j];
                }
        }
        __syncthreads();
    }
    float4 bias = *(const float4*)&pb[n0 + ty * 4];
#pragma unroll
    for (int r = 0; r < 4; ++r) {
        int m = m0 + tx * 4 + r;
        float4 v0 = make_float4(accA[r][0] + bias.x, accA[r][1] + bias.y,
                                accA[r][2] + bias.z, accA[r][3] + bias.w);
        float4 v1 = make_float4(accB[r][0] + bias.x, accB[r][1] + bias.y,
                                accB[r][2] + bias.z, accB[r][3] + bias.w);
        *(float4*)&out[(size_t)m * kC + n0 + ty * 4] = v0;
        *(float4*)&out[(size_t)(m + 64) * kC + n0 + ty * 4] = v1;
    }
}

// ---------------------------------------------------------------------------
// Host launcher
// ---------------------------------------------------------------------------
extern "C" void kernel_launch(void* const* d_in, const int* in_sizes, int n_in,
                              void* d_out, int out_size, void* d_ws, size_t ws_size,
                              hipStream_t stream) {
    const float* x      = (const float*)d_in[0];
    const float* qkv_w  = (const float*)d_in[1];
    const float* proj_w = (const float*)d_in[2];
    const float* proj_b = (const float*)d_in[3];
    const float* off_w2 = (const float*)d_in[4];
    const float* off_b2 = (const float*)d_in[5];
    const float* def_w2 = (const float*)d_in[6];
    const float* def_b2 = (const float*)d_in[7];
    const float* off_w3 = (const float*)d_in[8];
    const float* off_b3 = (const float*)d_in[9];
    const float* def_w3 = (const float*)d_in[10];
    const float* def_b3 = (const float*)d_in[11];
    float* out = (float*)d_out;

    float* ws   = (float*)d_ws;
    float* qkv  = ws;                               // 576 * M
    float* offb = qkv + (size_t)kNQKV * kM;         // 18 * M
    float* kd   = offb + (size_t)18 * kM;           // 64 * M
    float* vd   = kd + (size_t)kD * kM;             // 64 * M
    float* ao   = vd + (size_t)kD * kM;             // 192 * M
    float* dwt2 = ao + (size_t)kC * kM;             // 36864
    float* dwt3 = dwt2 + kD * kD * 9;               // 36864

    // 1. QKV projection
    qkv_gemm<<<dim3(kM / 128, kNQKV / 64), 256, 0, stream>>>(x, qkv_w, qkv);

    dw_transpose<<<144, 256, 0, stream>>>(def_w2, dwt2);
    dw_transpose<<<144, 256, 0, stream>>>(def_w3, dwt3);

    // 2. branch 0 (dil=1)
    attn_kernel<<<kB * kH, 512, 0, stream>>>(
        qkv, qkv + (size_t)kC * kHW, qkv + (size_t)2 * kC * kHW, ao,
        0, 1, kNQKV * kHW);

    // 3. branch 1 (dil=2)
    off_conv<<<kB * 18 * 16, 256, 0, stream>>>(qkv, off_w2, off_b2, offb, 1, 2);
    deform_conv2<<<kB * kH, 256, 0, stream>>>(
        qkv + (size_t)(kC + 1 * kD) * kHW, qkv + (size_t)(2 * kC + 1 * kD) * kHW,
        offb, dwt2, def_b2, kd, vd, kNQKV * kHW, 2);
    attn_kernel<<<kB * kH, 512, 0, stream>>>(qkv, kd, vd, ao, 1, 2, kD * kHW);

    // 4. branch 2 (dil=3)
    off_conv<<<kB * 18 * 16, 256, 0, stream>>>(qkv, off_w3, off_b3, offb, 2, 3);
    deform_conv2<<<kB * kH, 256, 0, stream>>>(
        qkv + (size_t)(kC + 2 * kD) * kHW, qkv + (size_t)(2 * kC + 2 * kD) * kHW,
        offb, dwt3, def_b3, kd, vd, kNQKV * kHW, 3);
    attn_kernel<<<kB * kH, 512, 0, stream>>>(qkv, kd, vd, ao, 2, 3, kD * kHW);

    // 5. output projection
    proj_gemm<<<dim3(kM / 128, kC / 64), 256, 0, stream>>>(ao, proj_w, proj_b, out);
}

// Round 3
// 703.064 us; speedup vs baseline: 1.5814x; 1.4807x over previous
//
#include <hip/hip_runtime.h>
#include <cmath>

// ---------------------------------------------------------------------------
// Problem constants (B=8, H=W=64, C=192, 3 dilation branches of d=64, heads=64)
// ---------------------------------------------------------------------------
#define kB    8
#define kH    64
#define kW    64
#define kHW   4096          // H*W
#define kC    192
#define kD    64            // channels per dilation branch == head_dim
#define kM    (kB * kHW)    // 32768 total pixels
#define kNQKV 576           // 3*C

// ---------------------------------------------------------------------------
// Kernel 1: QKV 1x1 conv == GEMM  out[m, o] = sum_k x[m,k] * qw[o,k]
// 128(m)x64(n) tile, 256 threads, 8x4 microtile, LDS transposed [kk][mm]
// so fragment reads are ds_read_b128 (2-way bank alias = free).
// ---------------------------------------------------------------------------
__global__ __launch_bounds__(256) void qkv_gemm(const float* __restrict__ x,
                                                const float* __restrict__ qw,
                                                float* __restrict__ qkv) {
    __shared__ float As[32][132];   // [kk][mm]
    __shared__ float Bs[32][68];    // [kk][nn]
    const int tid = threadIdx.x;
    const int tx = tid & 15;        // m quad within half-tile
    const int ty = tid >> 4;        // n quad
    const int m0 = blockIdx.x * 128;
    const int n0 = blockIdx.y * 64;

    float accA[4][4], accB[4][4];
#pragma unroll
    for (int r = 0; r < 4; ++r)
#pragma unroll
        for (int j = 0; j < 4; ++j) { accA[r][j] = 0.f; accB[r][j] = 0.f; }

    for (int k0 = 0; k0 < kC; k0 += 32) {
#pragma unroll
        for (int it = 0; it < 16; ++it) {
            int l = it * 256 + tid;
            int kk = l & 31, mm = l >> 5;
            As[kk][mm] = x[(size_t)(m0 + mm) * kC + k0 + kk];
        }
#pragma unroll
        for (int it = 0; it < 8; ++it) {
            int l = it * 256 + tid;
            int kk = l & 31, nn = l >> 5;
            Bs[kk][nn] = qw[(size_t)(n0 + nn) * kC + k0 + kk];
        }
        __syncthreads();
#pragma unroll
        for (int kk = 0; kk < 32; ++kk) {
            float4 a0 = *(const float4*)&As[kk][tx * 4];
            float4 a1 = *(const float4*)&As[kk][64 + tx * 4];
            float4 b  = *(const float4*)&Bs[kk][ty * 4];
            const float ar0[4] = {a0.x, a0.y, a0.z, a0.w};
            const float ar1[4] = {a1.x, a1.y, a1.z, a1.w};
            const float br[4]  = {b.x, b.y, b.z, b.w};
#pragma unroll
            for (int r = 0; r < 4; ++r)
#pragma unroll
                for (int j = 0; j < 4; ++j) {
                    accA[r][j] += ar0[r] * br[j];
                    accB[r][j] += ar1[r] * br[j];
                }
        }
        __syncthreads();
    }
    const int b_img = m0 >> 12;
    const int p = (m0 & 4095) + tx * 4;
#pragma unroll
    for (int j = 0; j < 4; ++j) {
        int n = n0 + ty * 4 + j;
        float* dst = &qkv[(size_t)(b_img * kNQKV + n) * kHW + p];
        *(float4*)dst = make_float4(accA[0][j], accA[1][j], accA[2][j], accA[3][j]);
        *(float4*)(dst + 64) = make_float4(accB[0][j], accB[1][j], accB[2][j], accB[3][j]);
    }
}

// ---------------------------------------------------------------------------
// Tiny transpose of deform weights: dw (o,c,kk) -> dwt (kk,c,o)
// ---------------------------------------------------------------------------
__global__ void dw_transpose(const float* __restrict__ dw, float* __restrict__ dwt) {
    int l = blockIdx.x * 256 + threadIdx.x;   // 64*64*9 = 36864
    if (l >= kD * kD * 9) return;
    int o = l / (kD * 9);
    int c = (l / 9) % kD;
    int kk = l % 9;
    dwt[(kk * kD + c) * kD + o] = dw[l];
}

// ---------------------------------------------------------------------------
// Kernel 2: offsets conv: 3x3 dilated conv, 64 -> 18 channels, padding = dil
// (j-blocks for the same pixel tile share bid%8 => same XCD L2: already good)
// ---------------------------------------------------------------------------
__global__ __launch_bounds__(256) void off_conv(const float* __restrict__ qkv,
                                                const float* __restrict__ ow,
                                                const float* __restrict__ ob,
                                                float* __restrict__ offb,
                                                int branch, int dil) {
    __shared__ float wsm[64 * 9];
    const int lb = blockIdx.x;
    const int pt = lb & 15;
    const int j = (lb >> 4) % 18;
    const int b = lb / (16 * 18);
    const int tid = threadIdx.x;
    for (int l = tid; l < 64 * 9; l += 256) wsm[l] = ow[j * 64 * 9 + l];
    __syncthreads();

    const int p = pt * 256 + tid;
    const int y = p >> 6, x = p & 63;
    const float* kin = qkv + ((size_t)b * kNQKV + kC + branch * kD) * kHW;
    float acc = ob[j];
    for (int c = 0; c < kD; ++c) {
        const float* pl = kin + (size_t)c * kHW;
#pragma unroll
        for (int ky = 0; ky < 3; ++ky) {
            int yy = y + (ky - 1) * dil;
#pragma unroll
            for (int kx = 0; kx < 3; ++kx) {
                int xx = x + (kx - 1) * dil;
                float v = 0.f;
                if (yy >= 0 && yy < kH && xx >= 0 && xx < kW) v = pl[yy * kW + xx];
                acc += v * wsm[c * 9 + ky * 3 + kx];
            }
        }
    }
    offb[((size_t)b * 18 + j) * kHW + p] = acc;
}

// ---------------------------------------------------------------------------
// Kernel 3: deformable 3x3 conv, ONE tensor (k or v) per block.
// Grid = 1024 logical blocks: t(2) x b(8) x y(64), XCD-swizzled so each XCD
// works a contiguous (t,b,y) chunk (concurrent neighbors share tap rows).
// LDS exactly 32KB (smp 16K + wkt 16K) -> 4-5 blocks/CU. Bilinear coords are
// computed in registers per sampling thread (no sid/swt LDS, 2 barriers/tap).
// ---------------------------------------------------------------------------
__global__ __launch_bounds__(256) void deform_one(const float* __restrict__ kbase,
                                                  const float* __restrict__ vbase,
                                                  const float* __restrict__ offb,
                                                  const float* __restrict__ dwt,
                                                  const float* __restrict__ db,
                                                  float* __restrict__ outk,
                                                  float* __restrict__ outv,
                                                  int bstride, int dil) {
    __shared__ float smp[64][64];   // [c][x]
    __shared__ float wkt[64][64];   // [c][o]

    const int lb = (blockIdx.x & 7) * 128 + (blockIdx.x >> 3);  // XCD swizzle (G=1024)
    const int t = lb >> 9;          // 0 = k, 1 = v
    const int b = (lb >> 6) & 7;
    const int y = lb & 63;
    const int tid = threadIdx.x;
    const int xs = tid & 63;        // sampling pixel
    const int cg = tid >> 6;        // channel group (16 ch each)
    const int tx = tid & 15;        // output pixel quad
    const int ty = tid >> 4;        // output channel quad

    const float* inb = (t ? vbase : kbase) + (size_t)b * bstride;
    float* outp = t ? outv : outk;

    float acc[4][4];
#pragma unroll
    for (int r = 0; r < 4; ++r)
#pragma unroll
        for (int j = 0; j < 4; ++j) acc[r][j] = 0.f;

    const float* offrow = offb + (size_t)b * 18 * kHW + y * kW + xs;

    for (int kk = 0; kk < 9; ++kk) {
        // --- per-thread bilinear coords for pixel xs (registers only) ---
        float oy = offrow[(size_t)(kk * 2 + 0) * kHW];
        float ox = offrow[(size_t)(kk * 2 + 1) * kHW];
        float py = (float)y + (float)((kk / 3 - 1) * dil) + oy;
        float px = (float)xs + (float)((kk % 3 - 1) * dil) + ox;
        float fy = floorf(py), fx = floorf(px);
        float wy = py - fy, wx = px - fx;
        int y0 = (int)fy, x0 = (int)fx;
        int y1 = y0 + 1, x1 = x0 + 1;
        int y0c = min(max(y0, 0), kH - 1), x0c = min(max(x0, 0), kW - 1);
        int y1c = min(max(y1, 0), kH - 1), x1c = min(max(x1, 0), kW - 1);
        bool vy0 = (y0 >= 0) & (y0 < kH), vx0 = (x0 >= 0) & (x0 < kW);
        bool vy1 = (y1 >= 0) & (y1 < kH), vx1 = (x1 >= 0) & (x1 < kW);
        const int i00 = y0c * kW + x0c, i01 = y0c * kW + x1c;
        const int i10 = y1c * kW + x0c, i11 = y1c * kW + x1c;
        const float w00 = (vy0 && vx0) ? (1.f - wy) * (1.f - wx) : 0.f;
        const float w01 = (vy0 && vx1) ? (1.f - wy) * wx : 0.f;
        const float w10 = (vy1 && vx0) ? wy * (1.f - wx) : 0.f;
        const float w11 = (vy1 && vx1) ? wy * wx : 0.f;

        // --- stage this tap's 64x64 weight slice ---
#pragma unroll
        for (int it = 0; it < 16; ++it) {
            int l = it * 256 + tid;
            wkt[l >> 6][l & 63] = dwt[(size_t)kk * kD * kD + l];
        }
        // --- sample my 16 channels at my pixel ---
#pragma unroll
        for (int cc = 0; cc < 16; ++cc) {
            int c = cg * 16 + cc;
            const float* pl = inb + (size_t)c * kHW;
            smp[c][xs] = w00 * pl[i00] + w01 * pl[i01] + w10 * pl[i10] + w11 * pl[i11];
        }
        __syncthreads();
        // --- outer product: acc[px_r][o_j] += smp[c][px] * wkt[c][o] ---
        for (int c = 0; c < kD; ++c) {
            float4 a = *(const float4*)&smp[c][tx * 4];
            float4 w = *(const float4*)&wkt[c][ty * 4];
            const float ar[4] = {a.x, a.y, a.z, a.w};
            const float wr[4] = {w.x, w.y, w.z, w.w};
#pragma unroll
            for (int r = 0; r < 4; ++r)
#pragma unroll
                for (int j = 0; j < 4; ++j) acc[r][j] += ar[r] * wr[j];
        }
        __syncthreads();
    }
#pragma unroll
    for (int j = 0; j < 4; ++j) {
        int o = ty * 4 + j;
        float bias = db[o];
        float4 v = make_float4(acc[0][j] + bias, acc[1][j] + bias,
                               acc[2][j] + bias, acc[3][j] + bias);
        *(float4*)&outp[((size_t)b * kD + o) * kHW + y * kW + tx * 4] = v;
    }
}

// ---------------------------------------------------------------------------
// Kernel 4: 9-tap local attention, one block per (b, row), XCD-swizzled.
// 512 threads = 64 px * 8 channel-groups. Partial QK -> LDS reduce ->
// softmax (zero-padded taps participate with score 0) -> PV.
// ---------------------------------------------------------------------------
__global__ __launch_bounds__(512) void attn_kernel(const float* __restrict__ qkv,
                                                   const float* __restrict__ ksrc,
                                                   const float* __restrict__ vsrc,
                                                   float* __restrict__ ao,
                                                   int branch, int dil, int kvstride) {
    __shared__ float part[9][8][64];
    const int lb = (blockIdx.x & 7) * 64 + (blockIdx.x >> 3);   // XCD swizzle (G=512)
    const int tid = threadIdx.x;
    const int x = tid & 63;
    const int g = tid >> 6;          // 0..7, wave-uniform
    const int b = lb >> 6;
    const int y = lb & 63;
    const int p = y * kW + x;
    const int pg = b * kHW + p;

    const float* qb = qkv + ((size_t)b * kNQKV + branch * kD) * kHW + p;
    const float* kb = ksrc + (size_t)b * kvstride;
    const float* vb = vsrc + (size_t)b * kvstride;

    int offs[9]; float msk[9];
#pragma unroll
    for (int kk = 0; kk < 9; ++kk) {
        int dy = (kk / 3 - 1) * dil, dx = (kk % 3 - 1) * dil;
        int yy = y + dy, xx = x + dx;
        bool v = (yy >= 0) & (yy < kH) & (xx >= 0) & (xx < kW);
        offs[kk] = v ? (p + dy * kW + dx) : 0;
        msk[kk] = v ? 1.f : 0.f;
    }
    float sc[9];
#pragma unroll
    for (int kk = 0; kk < 9; ++kk) sc[kk] = 0.f;
#pragma unroll
    for (int cc = 0; cc < 8; ++cc) {
        int c = g * 8 + cc;
        float qv = qb[(size_t)c * kHW];
        const float* kp = kb + (size_t)c * kHW;
#pragma unroll
        for (int kk = 0; kk < 9; ++kk) sc[kk] += qv * (msk[kk] * kp[offs[kk]]);
    }
#pragma unroll
    for (int kk = 0; kk < 9; ++kk) part[kk][g][x] = sc[kk];
    __syncthreads();

    float e[9], mx = -1e30f;
#pragma unroll
    for (int kk = 0; kk < 9; ++kk) {
        float s = 0.f;
#pragma unroll
        for (int gg = 0; gg < 8; ++gg) s += part[kk][gg][x];
        s *= 0.125f;
        e[kk] = s;
        mx = fmaxf(mx, s);
    }
    float ssum = 0.f;
#pragma unroll
    for (int kk = 0; kk < 9; ++kk) { e[kk] = __expf(e[kk] - mx); ssum += e[kk]; }
    float inv = 1.f / ssum;
#pragma unroll
    for (int kk = 0; kk < 9; ++kk) e[kk] = e[kk] * inv * msk[kk];

#pragma unroll
    for (int cc = 0; cc < 8; ++cc) {
        int c = g * 8 + cc;
        const float* vp = vb + (size_t)c * kHW;
        float o = 0.f;
#pragma unroll
        for (int kk = 0; kk < 9; ++kk) o += e[kk] * vp[offs[kk]];
        ao[(size_t)(branch * kD + c) * kM + pg] = o;
    }
}

// ---------------------------------------------------------------------------
// Kernel 5: output projection GEMM.  ao: (192, M) planar; pw: (192n, 192k).
// ---------------------------------------------------------------------------
__global__ __launch_bounds__(256) void proj_gemm(const float* __restrict__ ao,
                                                 const float* __restrict__ pw,
                                                 const float* __restrict__ pb,
                                                 float* __restrict__ out) {
    __shared__ float As[32][132];   // [kk][mm]
    __shared__ float Bs[32][68];    // [kk][nn]
    const int tid = threadIdx.x;
    const int tx = tid & 15;   // m quad
    const int ty = tid >> 4;   // n quad
    const int m0 = blockIdx.x * 128;
    const int n0 = blockIdx.y * 64;

    float accA[4][4], accB[4][4];
#pragma unroll
    for (int r = 0; r < 4; ++r)
#pragma unroll
        for (int j = 0; j < 4; ++j) { accA[r][j] = 0.f; accB[r][j] = 0.f; }

    for (int k0 = 0; k0 < kC; k0 += 32) {
#pragma unroll
        for (int it = 0; it < 16; ++it) {
            int l = it * 256 + tid;
            int mm = l & 127, kk = l >> 7;
            As[kk][mm] = ao[(size_t)(k0 + kk) * kM + m0 + mm];
        }
#pragma unroll
        for (int it = 0; it < 8; ++it) {
            int l = it * 256 + tid;
            int kk = l & 31, nn = l >> 5;
            Bs[kk][nn] = pw[(size_t)(n0 + nn) * kC + k0 + kk];
        }
        __syncthreads();
#pragma unroll
        for (int kk = 0; kk < 32; ++kk) {
            float4 a0 = *(const float4*)&As[kk][tx * 4];
            float4 a1 = *(const float4*)&As[kk][64 + tx * 4];
            float4 b  = *(const float4*)&Bs[kk][ty * 4];
            const float ar0[4] = {a0.x, a0.y, a0.z, a0.w};
            const float ar1[4] = {a1.x, a1.y, a1.z, a1.w};
            const float br[4]  = {b.x, b.y, b.z, b.w};
#pragma unroll
            for (int r = 0; r < 4; ++r)
#pragma unroll
                for (int j = 0; j < 4; ++j) {
                    accA[r][j] += ar0[r] * br[j];
                    accB[r][j] += ar1[r] * br[j];
                }
        }
        __syncthreads();
    }
    float4 bias = *(const float4*)&pb[n0 + ty * 4];
#pragma unroll
    for (int r = 0; r < 4; ++r) {
        int m = m0 + tx * 4 + r;
        float4 v0 = make_float4(accA[r][0] + bias.x, accA[r][1] + bias.y,
                                accA[r][2] + bias.z, accA[r][3] + bias.w);
        float4 v1 = make_float4(accB[r][0] + bias.x, accB[r][1] + bias.y,
                                accB[r][2] + bias.z, accB[r][3] + bias.w);
        *(float4*)&out[(size_t)m * kC + n0 + ty * 4] = v0;
        *(float4*)&out[(size_t)(m + 64) * kC + n0 + ty * 4] = v1;
    }
}

// ---------------------------------------------------------------------------
// Host launcher
// ---------------------------------------------------------------------------
extern "C" void kernel_launch(void* const* d_in, const int* in_sizes, int n_in,
                              void* d_out, int out_size, void* d_ws, size_t ws_size,
                              hipStream_t stream) {
    const float* x      = (const float*)d_in[0];
    const float* qkv_w  = (const float*)d_in[1];
    const float* proj_w = (const float*)d_in[2];
    const float* proj_b = (const float*)d_in[3];
    const float* off_w2 = (const float*)d_in[4];
    const float* off_b2 = (const float*)d_in[5];
    const float* def_w2 = (const float*)d_in[6];
    const float* def_b2 = (const float*)d_in[7];
    const float* off_w3 = (const float*)d_in[8];
    const float* off_b3 = (const float*)d_in[9];
    const float* def_w3 = (const float*)d_in[10];
    const float* def_b3 = (const float*)d_in[11];
    float* out = (float*)d_out;

    float* ws   = (float*)d_ws;
    float* qkv  = ws;                               // 576 * M
    float* offb = qkv + (size_t)kNQKV * kM;         // 18 * M
    float* kd   = offb + (size_t)18 * kM;           // 64 * M
    float* vd   = kd + (size_t)kD * kM;             // 64 * M
    float* ao   = vd + (size_t)kD * kM;             // 192 * M
    float* dwt2 = ao + (size_t)kC * kM;             // 36864
    float* dwt3 = dwt2 + kD * kD * 9;               // 36864

    // 1. QKV projection
    qkv_gemm<<<dim3(kM / 128, kNQKV / 64), 256, 0, stream>>>(x, qkv_w, qkv);

    dw_transpose<<<144, 256, 0, stream>>>(def_w2, dwt2);
    dw_transpose<<<144, 256, 0, stream>>>(def_w3, dwt3);

    // 2. branch 0 (dil=1)
    attn_kernel<<<kB * kH, 512, 0, stream>>>(
        qkv, qkv + (size_t)kC * kHW, qkv + (size_t)2 * kC * kHW, ao,
        0, 1, kNQKV * kHW);

    // 3. branch 1 (dil=2)
    off_conv<<<kB * 18 * 16, 256, 0, stream>>>(qkv, off_w2, off_b2, offb, 1, 2);
    deform_one<<<1024, 256, 0, stream>>>(
        qkv + (size_t)(kC + 1 * kD) * kHW, qkv + (size_t)(2 * kC + 1 * kD) * kHW,
        offb, dwt2, def_b2, kd, vd, kNQKV * kHW, 2);
    attn_kernel<<<kB * kH, 512, 0, stream>>>(qkv, kd, vd, ao, 1, 2, kD * kHW);

    // 4. branch 2 (dil=3)
    off_conv<<<kB * 18 * 16, 256, 0, stream>>>(qkv, off_w3, off_b3, offb, 2, 3);
    deform_one<<<1024, 256, 0, stream>>>(
        qkv + (size_t)(kC + 2 * kD) * kHW, qkv + (size_t)(2 * kC + 2 * kD) * kHW,
        offb, dwt3, def_b3, kd, vd, kNQKV * kHW, 3);
    attn_kernel<<<kB * kH, 512, 0, stream>>>(qkv, kd, vd, ao, 2, 3, kD * kHW);

    // 5. output projection
    proj_gemm<<<dim3(kM / 128, kC / 64), 256, 0, stream>>>(ao, proj_w, proj_b, out);
}

// Round 6
// 635.645 us; speedup vs baseline: 1.7492x; 1.1061x over previous
//
#include <hip/hip_runtime.h>
#include <cmath>

// ---------------------------------------------------------------------------
// Problem constants (B=8, H=W=64, C=192, 3 dilation branches of d=64, heads=64)
// ---------------------------------------------------------------------------
#define kB    8
#define kH    64
#define kW    64
#define kHW   4096          // H*W
#define kC    192
#define kD    64            // channels per dilation branch == head_dim
#define kM    (kB * kHW)    // 32768 total pixels
#define kNQKV 576           // 3*C

typedef unsigned short ushort_t;
typedef __attribute__((ext_vector_type(8))) short  s8v;   // 8 bf16 (4 VGPRs)
typedef __attribute__((ext_vector_type(4))) float  f4v;   // MFMA C/D frag

__device__ inline unsigned short bf16r(float f) {   // round-to-nearest-even
    union { float f; unsigned u; } v; v.f = f;
    unsigned u = v.u + 0x7FFFu + ((v.u >> 16) & 1u);
    return (unsigned short)(u >> 16);
}

// ---------------------------------------------------------------------------
// fp32 -> bf16 pairwise converter (dst as packed uint = 2 bf16)
// ---------------------------------------------------------------------------
__global__ void cvt_bf16(const float* __restrict__ src, unsigned* __restrict__ dst, int n2) {
    int i = blockIdx.x * 256 + threadIdx.x;
    if (i >= n2) return;
    float2 f = ((const float2*)src)[i];
    dst[i] = (unsigned)bf16r(f.x) | ((unsigned)bf16r(f.y) << 16);
}

// ---------------------------------------------------------------------------
// deform weights: dw (o,c,kk) fp32 -> dwtb[kk][o][c] bf16 (B-frag friendly:
// 8 consecutive c per 16B load for fixed o)
// ---------------------------------------------------------------------------
__global__ void dw_tb(const float* __restrict__ dw, ushort_t* __restrict__ dwtb) {
    int l = blockIdx.x * 256 + threadIdx.x;   // 64*64*9 = 36864
    if (l >= kD * kD * 9) return;
    int o = l / 576;
    int c = (l / 9) % 64;
    int kk = l % 9;
    dwtb[(kk * 64 + o) * 64 + c] = bf16r(dw[l]);
}

// ---------------------------------------------------------------------------
// Kernel 1: QKV projection via bf16 MFMA, LDS-free.
// out[m,n] = sum_k x[m,k]*qw[n,k].  A-frag: xb rows (k-contig), B-frag: qwb
// rows (k-contig). Wave = 16m x 64n, block = 4 waves = 64m x 64n.
// Output planar fp32: qkv[(b*576 + n)*HW + p].
// ---------------------------------------------------------------------------
__global__ __launch_bounds__(256) void qkv_mfma(const ushort_t* __restrict__ xb,
                                                const ushort_t* __restrict__ qwb,
                                                float* __restrict__ qkv) {
    const int tid  = threadIdx.x;
    const int lane = tid & 63;
    const int wave = tid >> 6;
    const int l15  = lane & 15;
    const int q    = lane >> 4;
    const int m0   = blockIdx.x * 64 + wave * 16;
    const int n0   = blockIdx.y * 64;

    f4v acc[4];
#pragma unroll
    for (int ob = 0; ob < 4; ++ob) acc[ob] = (f4v){0.f, 0.f, 0.f, 0.f};

    const ushort_t* ap = xb + (size_t)(m0 + l15) * kC + q * 8;
#pragma unroll
    for (int kc = 0; kc < 6; ++kc) {
        s8v a = *(const s8v*)(ap + kc * 32);
#pragma unroll
        for (int ob = 0; ob < 4; ++ob) {
            s8v b = *(const s8v*)(qwb + (size_t)(n0 + ob * 16 + l15) * kC + kc * 32 + q * 8);
            acc[ob] = __builtin_amdgcn_mfma_f32_16x16x32_bf16(a, b, acc[ob], 0, 0, 0);
        }
    }
    const int b_img = m0 >> 12;
    const int p = (m0 & 4095) + q * 4;   // D row = q*4 + reg
#pragma unroll
    for (int ob = 0; ob < 4; ++ob) {
        int n = n0 + ob * 16 + l15;      // D col = lane&15
        *(f4v*)&qkv[(size_t)(b_img * kNQKV + n) * kHW + p] = acc[ob];
    }
}

// ---------------------------------------------------------------------------
// Kernel 2: offsets conv: 3x3 dilated conv, 64 -> 18 channels (fp32, exact —
// offsets feed sampling coordinates)
// ---------------------------------------------------------------------------
__global__ __launch_bounds__(256) void off_conv(const float* __restrict__ qkv,
                                                const float* __restrict__ ow,
                                                const float* __restrict__ ob,
                                                float* __restrict__ offb,
                                                int branch, int dil) {
    __shared__ float wsm[64 * 9];
    const int lb = blockIdx.x;
    const int pt = lb & 15;
    const int j = (lb >> 4) % 18;
    const int b = lb / (16 * 18);
    const int tid = threadIdx.x;
    for (int l = tid; l < 64 * 9; l += 256) wsm[l] = ow[j * 64 * 9 + l];
    __syncthreads();

    const int p = pt * 256 + tid;
    const int y = p >> 6, x = p & 63;
    const float* kin = qkv + ((size_t)b * kNQKV + kC + branch * kD) * kHW;
    float acc = ob[j];
    for (int c = 0; c < kD; ++c) {
        const float* pl = kin + (size_t)c * kHW;
#pragma unroll
        for (int ky = 0; ky < 3; ++ky) {
            int yy = y + (ky - 1) * dil;
#pragma unroll
            for (int kx = 0; kx < 3; ++kx) {
                int xx = x + (kx - 1) * dil;
                float v = 0.f;
                if (yy >= 0 && yy < kH && xx >= 0 && xx < kW) v = pl[yy * kW + xx];
                acc += v * wsm[c * 9 + ky * 3 + kx];
            }
        }
    }
    offb[((size_t)b * 18 + j) * kHW + p] = acc;
}

// ---------------------------------------------------------------------------
// Kernel 3: deformable 3x3 conv via bf16 MFMA, LDS-free, barrier-free.
// Block = one (tensor t, batch b, row y): 64 px x 64 o.  Wave = 16 px x 64 o.
// Per tap: each lane bilinear-samples the 16 channels its A-frags need
// (A[m=lane&15][k=quad*8+j], chunks c<32 and c>=32) at pixel px=wave*16+l15;
// B-frags are 16B global loads from dwtb[kk][o][c] (L1-resident, 8KB/tap).
// Accumulators stay fp32 in registers across all 9 taps.
// ---------------------------------------------------------------------------
__global__ __launch_bounds__(256) void deform_mfma(const float* __restrict__ kbase,
                                                   const float* __restrict__ vbase,
                                                   const float* __restrict__ offb,
                                                   const ushort_t* __restrict__ dwtb,
                                                   const float* __restrict__ db,
                                                   float* __restrict__ outk,
                                                   float* __restrict__ outv,
                                                   int bstride, int dil) {
    const int lb = (blockIdx.x & 7) * 128 + (blockIdx.x >> 3);  // XCD swizzle (G=1024)
    const int t = lb >> 9;          // 0 = k, 1 = v
    const int b = (lb >> 6) & 7;
    const int y = lb & 63;
    const int tid  = threadIdx.x;
    const int lane = tid & 63;
    const int wave = tid >> 6;
    const int l15  = lane & 15;
    const int q    = lane >> 4;
    const int px   = wave * 16 + l15;   // A-operand pixel for this lane

    const float* inb = (t ? vbase : kbase) + (size_t)b * bstride;
    float* outp = t ? outv : outk;

    f4v acc[4];
#pragma unroll
    for (int ob = 0; ob < 4; ++ob) acc[ob] = (f4v){0.f, 0.f, 0.f, 0.f};

    const float* offrow = offb + (size_t)b * 18 * kHW + y * kW + px;

    for (int kk = 0; kk < 9; ++kk) {
        // --- bilinear coords for my pixel (registers only) ---
        float oy = offrow[(size_t)(kk * 2 + 0) * kHW];
        float ox = offrow[(size_t)(kk * 2 + 1) * kHW];
        float py = (float)y + (float)((kk / 3 - 1) * dil) + oy;
        float pxf = (float)px + (float)((kk % 3 - 1) * dil) + ox;
        float fy = floorf(py), fx = floorf(pxf);
        float wy = py - fy, wx = pxf - fx;
        int y0 = (int)fy, x0 = (int)fx;
        int y1 = y0 + 1, x1 = x0 + 1;
        int y0c = min(max(y0, 0), kH - 1), x0c = min(max(x0, 0), kW - 1);
        int y1c = min(max(y1, 0), kH - 1), x1c = min(max(x1, 0), kW - 1);
        bool vy0 = (y0 >= 0) & (y0 < kH), vx0 = (x0 >= 0) & (x0 < kW);
        bool vy1 = (y1 >= 0) & (y1 < kH), vx1 = (x1 >= 0) & (x1 < kW);
        const int i00 = y0c * kW + x0c, i01 = y0c * kW + x1c;
        const int i10 = y1c * kW + x0c, i11 = y1c * kW + x1c;
        const float w00 = (vy0 && vx0) ? (1.f - wy) * (1.f - wx) : 0.f;
        const float w01 = (vy0 && vx1) ? (1.f - wy) * wx : 0.f;
        const float w10 = (vy1 && vx0) ? wy * (1.f - wx) : 0.f;
        const float w11 = (vy1 && vx1) ? wy * wx : 0.f;

        // --- sample my 16 channels -> two A-frags ---
        s8v a0, a1;
#pragma unroll
        for (int j = 0; j < 8; ++j) {
            const float* pl = inb + (size_t)(q * 8 + j) * kHW;
            float v0 = w00 * pl[i00] + w01 * pl[i01] + w10 * pl[i10] + w11 * pl[i11];
            const float* pl2 = pl + (size_t)32 * kHW;
            float v1 = w00 * pl2[i00] + w01 * pl2[i01] + w10 * pl2[i10] + w11 * pl2[i11];
            a0[j] = (short)bf16r(v0);
            a1[j] = (short)bf16r(v1);
        }
        // --- B-frags straight from global (dwtb[kk][o][c]) + MFMA ---
        const ushort_t* wb = dwtb + (size_t)kk * 4096 + l15 * 64 + q * 8;
#pragma unroll
        for (int ob = 0; ob < 4; ++ob) {
            s8v b0 = *(const s8v*)(wb + ob * 1024);
            s8v b1 = *(const s8v*)(wb + ob * 1024 + 32);
            acc[ob] = __builtin_amdgcn_mfma_f32_16x16x32_bf16(a0, b0, acc[ob], 0, 0, 0);
            acc[ob] = __builtin_amdgcn_mfma_f32_16x16x32_bf16(a1, b1, acc[ob], 0, 0, 0);
        }
    }
#pragma unroll
    for (int ob = 0; ob < 4; ++ob) {
        int o = ob * 16 + l15;                       // D col
        float bias = db[o];
        f4v v = acc[ob];
        v.x += bias; v.y += bias; v.z += bias; v.w += bias;
        // D rows = px = wave*16 + q*4 + reg
        *(f4v*)&outp[((size_t)(b * kD + o)) * kHW + y * kW + wave * 16 + q * 4] = v;
    }
}

// ---------------------------------------------------------------------------
// Kernel 4: 9-tap local attention, one block per (b, row), XCD-swizzled.
// 512 threads = 64 px * 8 channel-groups. Partial QK -> LDS reduce ->
// softmax (zero-padded taps participate with score 0) -> PV.
// ---------------------------------------------------------------------------
__global__ __launch_bounds__(512) void attn_kernel(const float* __restrict__ qkv,
                                                   const float* __restrict__ ksrc,
                                                   const float* __restrict__ vsrc,
                                                   float* __restrict__ ao,
                                                   int branch, int dil, int kvstride) {
    __shared__ float part[9][8][64];
    const int lb = (blockIdx.x & 7) * 64 + (blockIdx.x >> 3);   // XCD swizzle (G=512)
    const int tid = threadIdx.x;
    const int x = tid & 63;
    const int g = tid >> 6;          // 0..7, wave-uniform
    const int b = lb >> 6;
    const int y = lb & 63;
    const int p = y * kW + x;
    const int pg = b * kHW + p;

    const float* qb = qkv + ((size_t)b * kNQKV + branch * kD) * kHW + p;
    const float* kb = ksrc + (size_t)b * kvstride;
    const float* vb = vsrc + (size_t)b * kvstride;

    int offs[9]; float msk[9];
#pragma unroll
    for (int kk = 0; kk < 9; ++kk) {
        int dy = (kk / 3 - 1) * dil, dx = (kk % 3 - 1) * dil;
        int yy = y + dy, xx = x + dx;
        bool v = (yy >= 0) & (yy < kH) & (xx >= 0) & (xx < kW);
        offs[kk] = v ? (p + dy * kW + dx) : 0;
        msk[kk] = v ? 1.f : 0.f;
    }
    float sc[9];
#pragma unroll
    for (int kk = 0; kk < 9; ++kk) sc[kk] = 0.f;
#pragma unroll
    for (int cc = 0; cc < 8; ++cc) {
        int c = g * 8 + cc;
        float qv = qb[(size_t)c * kHW];
        const float* kp = kb + (size_t)c * kHW;
#pragma unroll
        for (int kk = 0; kk < 9; ++kk) sc[kk] += qv * (msk[kk] * kp[offs[kk]]);
    }
#pragma unroll
    for (int kk = 0; kk < 9; ++kk) part[kk][g][x] = sc[kk];
    __syncthreads();

    float e[9], mx = -1e30f;
#pragma unroll
    for (int kk = 0; kk < 9; ++kk) {
        float s = 0.f;
#pragma unroll
        for (int gg = 0; gg < 8; ++gg) s += part[kk][gg][x];
        s *= 0.125f;
        e[kk] = s;
        mx = fmaxf(mx, s);
    }
    float ssum = 0.f;
#pragma unroll
    for (int kk = 0; kk < 9; ++kk) { e[kk] = __expf(e[kk] - mx); ssum += e[kk]; }
    float inv = 1.f / ssum;
#pragma unroll
    for (int kk = 0; kk < 9; ++kk) e[kk] = e[kk] * inv * msk[kk];

#pragma unroll
    for (int cc = 0; cc < 8; ++cc) {
        int c = g * 8 + cc;
        const float* vp = vb + (size_t)c * kHW;
        float o = 0.f;
#pragma unroll
        for (int kk = 0; kk < 9; ++kk) o += e[kk] * vp[offs[kk]];
        ao[(size_t)(branch * kD + c) * kM + pg] = o;
    }
}

// ---------------------------------------------------------------------------
// Kernel 5: output projection GEMM (fp32 SIMT).  ao: (192, M) planar.
// ---------------------------------------------------------------------------
__global__ __launch_bounds__(256) void proj_gemm(const float* __restrict__ ao,
                                                 const float* __restrict__ pw,
                                                 const float* __restrict__ pb,
                                                 float* __restrict__ out) {
    __shared__ float As[32][132];   // [kk][mm]
    __shared__ float Bs[32][68];    // [kk][nn]
    const int tid = threadIdx.x;
    const int tx = tid & 15;   // m quad
    const int ty = tid >> 4;   // n quad
    const int m0 = blockIdx.x * 128;
    const int n0 = blockIdx.y * 64;

    float accA[4][4], accB[4][4];
#pragma unroll
    for (int r = 0; r < 4; ++r)
#pragma unroll
        for (int j = 0; j < 4; ++j) { accA[r][j] = 0.f; accB[r][j] = 0.f; }

    for (int k0 = 0; k0 < kC; k0 += 32) {
#pragma unroll
        for (int it = 0; it < 16; ++it) {
            int l = it * 256 + tid;
            int mm = l & 127, kk = l >> 7;
            As[kk][mm] = ao[(size_t)(k0 + kk) * kM + m0 + mm];
        }
#pragma unroll
        for (int it = 0; it < 8; ++it) {
            int l = it * 256 + tid;
            int kk = l & 31, nn = l >> 5;
            Bs[kk][nn] = pw[(size_t)(n0 + nn) * kC + k0 + kk];
        }
        __syncthreads();
#pragma unroll
        for (int kk = 0; kk < 32; ++kk) {
            float4 a0 = *(const float4*)&As[kk][tx * 4];
            float4 a1 = *(const float4*)&As[kk][64 + tx * 4];
            float4 b  = *(const float4*)&Bs[kk][ty * 4];
            const float ar0[4] = {a0.x, a0.y, a0.z, a0.w};
            const float ar1[4] = {a1.x, a1.y, a1.z, a1.w};
            const float br[4]  = {b.x, b.y, b.z, b.w};
#pragma unroll
            for (int r = 0; r < 4; ++r)
#pragma unroll
                for (int j = 0; j < 4; ++j) {
                    accA[r][j] += ar0[r] * br[j];
                    accB[r][j] += ar1[r] * br[j];
                }
        }
        __syncthreads();
    }
    float4 bias = *(const float4*)&pb[n0 + ty * 4];
#pragma unroll
    for (int r = 0; r < 4; ++r) {
        int m = m0 + tx * 4 + r;
        float4 v0 = make_float4(accA[r][0] + bias.x, accA[r][1] + bias.y,
                                accA[r][2] + bias.z, accA[r][3] + bias.w);
        float4 v1 = make_float4(accB[r][0] + bias.x, accB[r][1] + bias.y,
                                accB[r][2] + bias.z, accB[r][3] + bias.w);
        *(float4*)&out[(size_t)m * kC + n0 + ty * 4] = v0;
        *(float4*)&out[(size_t)(m + 64) * kC + n0 + ty * 4] = v1;
    }
}

// ---------------------------------------------------------------------------
// Host launcher.
// Workspace budget: total ws usage = 914 planes * kM floats = ~119.8 MB.
// bf16 staging is aliased INTO the ao region (dead until attn kernels run).
// PLANE-SIZE ACCOUNTING (round-5 bug): one ao "plane" = kM floats = 128 KiB.
//   xb    needs kM*kC bf16   = 12 MiB  = exactly 96 planes -> planes 0..95
//   qwb   needs 576*192 bf16 = 216 KiB = 1.69 planes       -> planes 160..161  (TWO planes!)
//   dwtb2 needs 36864 bf16   = 72 KiB  = <1 plane          -> plane 162
//   dwtb3 needs 36864 bf16   = 72 KiB  = <1 plane          -> plane 163
// Lifetimes (stream order): xb,qwb consumed by qkv_mfma before attn0 writes
// planes 0..63; attn1 writes 64..127; dwtb2 consumed by deform#1 before attn1;
// dwtb3 consumed by deform#2 before attn2 writes 128..191 (incl. 160..163).
// ---------------------------------------------------------------------------
extern "C" void kernel_launch(void* const* d_in, const int* in_sizes, int n_in,
                              void* d_out, int out_size, void* d_ws, size_t ws_size,
                              hipStream_t stream) {
    const float* x      = (const float*)d_in[0];
    const float* qkv_w  = (const float*)d_in[1];
    const float* proj_w = (const float*)d_in[2];
    const float* proj_b = (const float*)d_in[3];
    const float* off_w2 = (const float*)d_in[4];
    const float* off_b2 = (const float*)d_in[5];
    const float* def_w2 = (const float*)d_in[6];
    const float* def_b2 = (const float*)d_in[7];
    const float* off_w3 = (const float*)d_in[8];
    const float* off_b3 = (const float*)d_in[9];
    const float* def_w3 = (const float*)d_in[10];
    const float* def_b3 = (const float*)d_in[11];
    float* out = (float*)d_out;

    float* ws   = (float*)d_ws;
    float* qkv  = ws;                               // 576 * M  fp32 planar
    float* offb = qkv + (size_t)kNQKV * kM;         // 18 * M
    float* kd   = offb + (size_t)18 * kM;           // 64 * M
    float* vd   = kd + (size_t)kD * kM;             // 64 * M
    float* ao   = vd + (size_t)kD * kM;             // 192 * M
    // bf16 staging aliased INTO ao (see plane accounting above)
    ushort_t* xb    = (ushort_t*)ao;                          // planes 0..95
    ushort_t* qwb   = (ushort_t*)(ao + (size_t)160 * kM);     // planes 160..161
    ushort_t* dwtb2 = (ushort_t*)(ao + (size_t)162 * kM);     // plane 162
    ushort_t* dwtb3 = (ushort_t*)(ao + (size_t)163 * kM);     // plane 163

    // 0. bf16 conversions (x, qkv_w) and deform-weight transposes
    cvt_bf16<<<(kM * kC / 2 + 255) / 256, 256, 0, stream>>>(x, (unsigned*)xb, kM * kC / 2);
    cvt_bf16<<<(kNQKV * kC / 2 + 255) / 256, 256, 0, stream>>>(qkv_w, (unsigned*)qwb, kNQKV * kC / 2);
    dw_tb<<<144, 256, 0, stream>>>(def_w2, dwtb2);
    dw_tb<<<144, 256, 0, stream>>>(def_w3, dwtb3);

    // 1. QKV projection (bf16 MFMA) — consumes xb, qwb
    qkv_mfma<<<dim3(kM / 64, kNQKV / 64), 256, 0, stream>>>(xb, qwb, qkv);

    // 2. branch 0 (dil=1) — attn0 overwrites ao planes 0..63 (xb region, dead)
    attn_kernel<<<kB * kH, 512, 0, stream>>>(
        qkv, qkv + (size_t)kC * kHW, qkv + (size_t)2 * kC * kHW, ao,
        0, 1, kNQKV * kHW);

    // 3. branch 1 (dil=2) — deform consumes dwtb2 before attn1 writes 64..127
    off_conv<<<kB * 18 * 16, 256, 0, stream>>>(qkv, off_w2, off_b2, offb, 1, 2);
    deform_mfma<<<1024, 256, 0, stream>>>(
        qkv + (size_t)(kC + 1 * kD) * kHW, qkv + (size_t)(2 * kC + 1 * kD) * kHW,
        offb, dwtb2, def_b2, kd, vd, kNQKV * kHW, 2);
    attn_kernel<<<kB * kH, 512, 0, stream>>>(qkv, kd, vd, ao, 1, 2, kD * kHW);

    // 4. branch 2 (dil=3) — deform consumes dwtb3 before attn2 writes 128..191
    off_conv<<<kB * 18 * 16, 256, 0, stream>>>(qkv, off_w3, off_b3, offb, 2, 3);
    deform_mfma<<<1024, 256, 0, stream>>>(
        qkv + (size_t)(kC + 2 * kD) * kHW, qkv + (size_t)(2 * kC + 2 * kD) * kHW,
        offb, dwtb3, def_b3, kd, vd, kNQKV * kHW, 3);
    attn_kernel<<<kB * kH, 512, 0, stream>>>(qkv, kd, vd, ao, 2, 3, kD * kHW);

    // 5. output projection (fp32)
    proj_gemm<<<dim3(kM / 128, kC / 64), 256, 0, stream>>>(ao, proj_w, proj_b, out);
}

// Round 7
// 558.732 us; speedup vs baseline: 1.9899x; 1.1377x over previous
//
#include <hip/hip_runtime.h>
#include <cmath>

// ---------------------------------------------------------------------------
// Problem constants (B=8, H=W=64, C=192, 3 dilation branches of d=64, heads=64)
// ---------------------------------------------------------------------------
#define kB    8
#define kH    64
#define kW    64
#define kHW   4096          // H*W
#define kC    192
#define kD    64            // channels per dilation branch == head_dim
#define kM    (kB * kHW)    // 32768 total pixels
#define kNQKV 576           // 3*C

typedef unsigned short ushort_t;
typedef __attribute__((ext_vector_type(8))) short  s8v;   // 8 bf16 (4 VGPRs)
typedef __attribute__((ext_vector_type(4))) float  f4v;   // MFMA C/D frag

__device__ inline unsigned short bf16r(float f) {   // round-to-nearest-even
    union { float f; unsigned u; } v; v.f = f;
    unsigned u = v.u + 0x7FFFu + ((v.u >> 16) & 1u);
    return (unsigned short)(u >> 16);
}
__device__ inline float bfu(short s) {              // bf16 -> fp32
    union { unsigned u; float f; } v;
    v.u = ((unsigned)(unsigned short)s) << 16;
    return v.f;
}

// ---------------------------------------------------------------------------
// fp32 -> bf16 pairwise converter (dst as packed uint = 2 bf16)
// ---------------------------------------------------------------------------
__global__ void cvt_bf16(const float* __restrict__ src, unsigned* __restrict__ dst, int n2) {
    int i = blockIdx.x * 256 + threadIdx.x;
    if (i >= n2) return;
    float2 f = ((const float2*)src)[i];
    dst[i] = (unsigned)bf16r(f.x) | ((unsigned)bf16r(f.y) << 16);
}

// ---------------------------------------------------------------------------
// deform weights: dw (o,c,kk) fp32 -> dwtb[kk][o][c] bf16 (B-frag friendly:
// 8 consecutive c per 16B load for fixed o)
// ---------------------------------------------------------------------------
__global__ void dw_tb(const float* __restrict__ dw, ushort_t* __restrict__ dwtb) {
    int l = blockIdx.x * 256 + threadIdx.x;   // 64*64*9 = 36864
    if (l >= kD * kD * 9) return;
    int o = l / 576;
    int c = (l / 9) % 64;
    int kk = l % 9;
    dwtb[(kk * 64 + o) * 64 + c] = bf16r(dw[l]);
}

// ---------------------------------------------------------------------------
// Repack: fp32 planar (64ch, plane stride kHW, batch stride bstride) ->
// bf16 pixel-major [b][p][c] for k AND v. One thread per pixel, 64 coalesced
// plane reads, 8x16B contiguous stores. 256 blocks.
// ---------------------------------------------------------------------------
__global__ __launch_bounds__(256) void repack_px(const float* __restrict__ kbase,
                                                 const float* __restrict__ vbase,
                                                 ushort_t* __restrict__ kpx,
                                                 ushort_t* __restrict__ vpx,
                                                 int bstride) {
    const int t  = blockIdx.x >> 7;           // 0=k, 1=v
    const int b  = (blockIdx.x >> 4) & 7;
    const int p  = (blockIdx.x & 15) * 256 + threadIdx.x;
    const float* in = (t ? vbase : kbase) + (size_t)b * bstride + p;
    ushort_t* outp = (t ? vpx : kpx) + ((size_t)b * kHW + p) * 64;
    unsigned buf[32];
#pragma unroll
    for (int c = 0; c < 32; ++c) {
        float f0 = in[(size_t)(2 * c) * kHW];
        float f1 = in[(size_t)(2 * c + 1) * kHW];
        buf[c] = (unsigned)bf16r(f0) | ((unsigned)bf16r(f1) << 16);
    }
#pragma unroll
    for (int i = 0; i < 8; ++i)
        ((uint4*)outp)[i] = make_uint4(buf[i * 4], buf[i * 4 + 1], buf[i * 4 + 2], buf[i * 4 + 3]);
}

// ---------------------------------------------------------------------------
// Kernel 1: QKV projection via bf16 MFMA, LDS-free.
// ---------------------------------------------------------------------------
__global__ __launch_bounds__(256) void qkv_mfma(const ushort_t* __restrict__ xb,
                                                const ushort_t* __restrict__ qwb,
                                                float* __restrict__ qkv) {
    const int tid  = threadIdx.x;
    const int lane = tid & 63;
    const int wave = tid >> 6;
    const int l15  = lane & 15;
    const int q    = lane >> 4;
    const int m0   = blockIdx.x * 64 + wave * 16;
    const int n0   = blockIdx.y * 64;

    f4v acc[4];
#pragma unroll
    for (int ob = 0; ob < 4; ++ob) acc[ob] = (f4v){0.f, 0.f, 0.f, 0.f};

    const ushort_t* ap = xb + (size_t)(m0 + l15) * kC + q * 8;
#pragma unroll
    for (int kc = 0; kc < 6; ++kc) {
        s8v a = *(const s8v*)(ap + kc * 32);
#pragma unroll
        for (int ob = 0; ob < 4; ++ob) {
            s8v b = *(const s8v*)(qwb + (size_t)(n0 + ob * 16 + l15) * kC + kc * 32 + q * 8);
            acc[ob] = __builtin_amdgcn_mfma_f32_16x16x32_bf16(a, b, acc[ob], 0, 0, 0);
        }
    }
    const int b_img = m0 >> 12;
    const int p = (m0 & 4095) + q * 4;   // D row = q*4 + reg
#pragma unroll
    for (int ob = 0; ob < 4; ++ob) {
        int n = n0 + ob * 16 + l15;      // D col = lane&15
        *(f4v*)&qkv[(size_t)(b_img * kNQKV + n) * kHW + p] = acc[ob];
    }
}

// ---------------------------------------------------------------------------
// Kernel 2: offsets conv: 3x3 dilated conv, 64 -> 18 channels (fp32, exact —
// offsets feed sampling coordinates)
// ---------------------------------------------------------------------------
__global__ __launch_bounds__(256) void off_conv(const float* __restrict__ qkv,
                                                const float* __restrict__ ow,
                                                const float* __restrict__ ob,
                                                float* __restrict__ offb,
                                                int branch, int dil) {
    __shared__ float wsm[64 * 9];
    const int lb = blockIdx.x;
    const int pt = lb & 15;
    const int j = (lb >> 4) % 18;
    const int b = lb / (16 * 18);
    const int tid = threadIdx.x;
    for (int l = tid; l < 64 * 9; l += 256) wsm[l] = ow[j * 64 * 9 + l];
    __syncthreads();

    const int p = pt * 256 + tid;
    const int y = p >> 6, x = p & 63;
    const float* kin = qkv + ((size_t)b * kNQKV + kC + branch * kD) * kHW;
    float acc = ob[j];
    for (int c = 0; c < kD; ++c) {
        const float* pl = kin + (size_t)c * kHW;
#pragma unroll
        for (int ky = 0; ky < 3; ++ky) {
            int yy = y + (ky - 1) * dil;
#pragma unroll
            for (int kx = 0; kx < 3; ++kx) {
                int xx = x + (kx - 1) * dil;
                float v = 0.f;
                if (yy >= 0 && yy < kH && xx >= 0 && xx < kW) v = pl[yy * kW + xx];
                acc += v * wsm[c * 9 + ky * 3 + kx];
            }
        }
    }
    offb[((size_t)b * 18 + j) * kHW + p] = acc;
}

// ---------------------------------------------------------------------------
// Kernel 3: deformable 3x3 conv via bf16 MFMA, LDS-free, barrier-free.
// Input is bf16 PIXEL-MAJOR [b][p][64c]: one bilinear corner for one lane's
// 16 channels = two 16B loads (was 64 scalar 4B loads per tap in round 6's
// planar version — VMEM-issue-bound at VALUBusy 10.7%).
// Block = one (tensor t, batch b, row y): 64 px x 64 o.  Wave = 16 px x 64 o.
// Accumulators stay fp32 in registers across all 9 taps.
// ---------------------------------------------------------------------------
__global__ __launch_bounds__(256) void deform_mfma(const ushort_t* __restrict__ kpx,
                                                   const ushort_t* __restrict__ vpx,
                                                   const float* __restrict__ offb,
                                                   const ushort_t* __restrict__ dwtb,
                                                   const float* __restrict__ db,
                                                   float* __restrict__ outk,
                                                   float* __restrict__ outv,
                                                   int dil) {
    const int lb = (blockIdx.x & 7) * 128 + (blockIdx.x >> 3);  // XCD swizzle (G=1024)
    const int t = lb >> 9;          // 0 = k, 1 = v
    const int b = (lb >> 6) & 7;
    const int y = lb & 63;
    const int tid  = threadIdx.x;
    const int lane = tid & 63;
    const int wave = tid >> 6;
    const int l15  = lane & 15;
    const int q    = lane >> 4;
    const int px   = wave * 16 + l15;   // A-operand pixel for this lane

    const ushort_t* inpx = (t ? vpx : kpx) + (size_t)b * kHW * 64 + q * 8;
    float* outp = t ? outv : outk;

    f4v acc[4];
#pragma unroll
    for (int ob = 0; ob < 4; ++ob) acc[ob] = (f4v){0.f, 0.f, 0.f, 0.f};

    const float* offrow = offb + (size_t)b * 18 * kHW + y * kW + px;

    for (int kk = 0; kk < 9; ++kk) {
        // --- bilinear coords for my pixel (registers only) ---
        float oy = offrow[(size_t)(kk * 2 + 0) * kHW];
        float ox = offrow[(size_t)(kk * 2 + 1) * kHW];
        float py = (float)y + (float)((kk / 3 - 1) * dil) + oy;
        float pxf = (float)px + (float)((kk % 3 - 1) * dil) + ox;
        float fy = floorf(py), fx = floorf(pxf);
        float wy = py - fy, wx = pxf - fx;
        int y0 = (int)fy, x0 = (int)fx;
        int y1 = y0 + 1, x1 = x0 + 1;
        int y0c = min(max(y0, 0), kH - 1), x0c = min(max(x0, 0), kW - 1);
        int y1c = min(max(y1, 0), kH - 1), x1c = min(max(x1, 0), kW - 1);
        bool vy0 = (y0 >= 0) & (y0 < kH), vx0 = (x0 >= 0) & (x0 < kW);
        bool vy1 = (y1 >= 0) & (y1 < kH), vx1 = (x1 >= 0) & (x1 < kW);
        const size_t i00 = (size_t)(y0c * kW + x0c) * 64;
        const size_t i01 = (size_t)(y0c * kW + x1c) * 64;
        const size_t i10 = (size_t)(y1c * kW + x0c) * 64;
        const size_t i11 = (size_t)(y1c * kW + x1c) * 64;
        const float w00 = (vy0 && vx0) ? (1.f - wy) * (1.f - wx) : 0.f;
        const float w01 = (vy0 && vx1) ? (1.f - wy) * wx : 0.f;
        const float w10 = (vy1 && vx0) ? wy * (1.f - wx) : 0.f;
        const float w11 = (vy1 && vx1) ? wy * wx : 0.f;

        // --- 8 x 16B corner loads (16 contiguous channels each corner) ---
        s8v c00a = *(const s8v*)(inpx + i00);
        s8v c00b = *(const s8v*)(inpx + i00 + 32);
        s8v c01a = *(const s8v*)(inpx + i01);
        s8v c01b = *(const s8v*)(inpx + i01 + 32);
        s8v c10a = *(const s8v*)(inpx + i10);
        s8v c10b = *(const s8v*)(inpx + i10 + 32);
        s8v c11a = *(const s8v*)(inpx + i11);
        s8v c11b = *(const s8v*)(inpx + i11 + 32);

        s8v a0, a1;
#pragma unroll
        for (int j = 0; j < 8; ++j) {
            float v0 = w00 * bfu(c00a[j]) + w01 * bfu(c01a[j]) +
                       w10 * bfu(c10a[j]) + w11 * bfu(c11a[j]);
            float v1 = w00 * bfu(c00b[j]) + w01 * bfu(c01b[j]) +
                       w10 * bfu(c10b[j]) + w11 * bfu(c11b[j]);
            a0[j] = (short)bf16r(v0);
            a1[j] = (short)bf16r(v1);
        }
        // --- B-frags straight from global (dwtb[kk][o][c]) + MFMA ---
        const ushort_t* wb = dwtb + (size_t)kk * 4096 + l15 * 64 + q * 8;
#pragma unroll
        for (int ob = 0; ob < 4; ++ob) {
            s8v b0 = *(const s8v*)(wb + ob * 1024);
            s8v b1 = *(const s8v*)(wb + ob * 1024 + 32);
            acc[ob] = __builtin_amdgcn_mfma_f32_16x16x32_bf16(a0, b0, acc[ob], 0, 0, 0);
            acc[ob] = __builtin_amdgcn_mfma_f32_16x16x32_bf16(a1, b1, acc[ob], 0, 0, 0);
        }
    }
#pragma unroll
    for (int ob = 0; ob < 4; ++ob) {
        int o = ob * 16 + l15;                       // D col
        float bias = db[o];
        f4v v = acc[ob];
        v.x += bias; v.y += bias; v.z += bias; v.w += bias;
        // D rows = px = wave*16 + q*4 + reg
        *(f4v*)&outp[((size_t)(b * kD + o)) * kHW + y * kW + wave * 16 + q * 4] = v;
    }
}

// ---------------------------------------------------------------------------
// Kernel 4: 9-tap local attention, one block per (b, row), XCD-swizzled.
// 512 threads = 64 px * 8 channel-groups. Partial QK -> LDS reduce ->
// softmax (zero-padded taps participate with score 0) -> PV.
// ---------------------------------------------------------------------------
__global__ __launch_bounds__(512) void attn_kernel(const float* __restrict__ qkv,
                                                   const float* __restrict__ ksrc,
                                                   const float* __restrict__ vsrc,
                                                   float* __restrict__ ao,
                                                   int branch, int dil, int kvstride) {
    __shared__ float part[9][8][64];
    const int lb = (blockIdx.x & 7) * 64 + (blockIdx.x >> 3);   // XCD swizzle (G=512)
    const int tid = threadIdx.x;
    const int x = tid & 63;
    const int g = tid >> 6;          // 0..7, wave-uniform
    const int b = lb >> 6;
    const int y = lb & 63;
    const int p = y * kW + x;
    const int pg = b * kHW + p;

    const float* qb = qkv + ((size_t)b * kNQKV + branch * kD) * kHW + p;
    const float* kb = ksrc + (size_t)b * kvstride;
    const float* vb = vsrc + (size_t)b * kvstride;

    int offs[9]; float msk[9];
#pragma unroll
    for (int kk = 0; kk < 9; ++kk) {
        int dy = (kk / 3 - 1) * dil, dx = (kk % 3 - 1) * dil;
        int yy = y + dy, xx = x + dx;
        bool v = (yy >= 0) & (yy < kH) & (xx >= 0) & (xx < kW);
        offs[kk] = v ? (p + dy * kW + dx) : 0;
        msk[kk] = v ? 1.f : 0.f;
    }
    float sc[9];
#pragma unroll
    for (int kk = 0; kk < 9; ++kk) sc[kk] = 0.f;
#pragma unroll
    for (int cc = 0; cc < 8; ++cc) {
        int c = g * 8 + cc;
        float qv = qb[(size_t)c * kHW];
        const float* kp = kb + (size_t)c * kHW;
#pragma unroll
        for (int kk = 0; kk < 9; ++kk) sc[kk] += qv * (msk[kk] * kp[offs[kk]]);
    }
#pragma unroll
    for (int kk = 0; kk < 9; ++kk) part[kk][g][x] = sc[kk];
    __syncthreads();

    float e[9], mx = -1e30f;
#pragma unroll
    for (int kk = 0; kk < 9; ++kk) {
        float s = 0.f;
#pragma unroll
        for (int gg = 0; gg < 8; ++gg) s += part[kk][gg][x];
        s *= 0.125f;
        e[kk] = s;
        mx = fmaxf(mx, s);
    }
    float ssum = 0.f;
#pragma unroll
    for (int kk = 0; kk < 9; ++kk) { e[kk] = __expf(e[kk] - mx); ssum += e[kk]; }
    float inv = 1.f / ssum;
#pragma unroll
    for (int kk = 0; kk < 9; ++kk) e[kk] = e[kk] * inv * msk[kk];

#pragma unroll
    for (int cc = 0; cc < 8; ++cc) {
        int c = g * 8 + cc;
        const float* vp = vb + (size_t)c * kHW;
        float o = 0.f;
#pragma unroll
        for (int kk = 0; kk < 9; ++kk) o += e[kk] * vp[offs[kk]];
        ao[(size_t)(branch * kD + c) * kM + pg] = o;
    }
}

// ---------------------------------------------------------------------------
// Kernel 5: output projection GEMM (fp32 SIMT).  ao: (192, M) planar.
// ---------------------------------------------------------------------------
__global__ __launch_bounds__(256) void proj_gemm(const float* __restrict__ ao,
                                                 const float* __restrict__ pw,
                                                 const float* __restrict__ pb,
                                                 float* __restrict__ out) {
    __shared__ float As[32][132];   // [kk][mm]
    __shared__ float Bs[32][68];    // [kk][nn]
    const int tid = threadIdx.x;
    const int tx = tid & 15;   // m quad
    const int ty = tid >> 4;   // n quad
    const int m0 = blockIdx.x * 128;
    const int n0 = blockIdx.y * 64;

    float accA[4][4], accB[4][4];
#pragma unroll
    for (int r = 0; r < 4; ++r)
#pragma unroll
        for (int j = 0; j < 4; ++j) { accA[r][j] = 0.f; accB[r][j] = 0.f; }

    for (int k0 = 0; k0 < kC; k0 += 32) {
#pragma unroll
        for (int it = 0; it < 16; ++it) {
            int l = it * 256 + tid;
            int mm = l & 127, kk = l >> 7;
            As[kk][mm] = ao[(size_t)(k0 + kk) * kM + m0 + mm];
        }
#pragma unroll
        for (int it = 0; it < 8; ++it) {
            int l = it * 256 + tid;
            int kk = l & 31, nn = l >> 5;
            Bs[kk][nn] = pw[(size_t)(n0 + nn) * kC + k0 + kk];
        }
        __syncthreads();
#pragma unroll
        for (int kk = 0; kk < 32; ++kk) {
            float4 a0 = *(const float4*)&As[kk][tx * 4];
            float4 a1 = *(const float4*)&As[kk][64 + tx * 4];
            float4 b  = *(const float4*)&Bs[kk][ty * 4];
            const float ar0[4] = {a0.x, a0.y, a0.z, a0.w};
            const float ar1[4] = {a1.x, a1.y, a1.z, a1.w};
            const float br[4]  = {b.x, b.y, b.z, b.w};
#pragma unroll
            for (int r = 0; r < 4; ++r)
#pragma unroll
                for (int j = 0; j < 4; ++j) {
                    accA[r][j] += ar0[r] * br[j];
                    accB[r][j] += ar1[r] * br[j];
                }
        }
        __syncthreads();
    }
    float4 bias = *(const float4*)&pb[n0 + ty * 4];
#pragma unroll
    for (int r = 0; r < 4; ++r) {
        int m = m0 + tx * 4 + r;
        float4 v0 = make_float4(accA[r][0] + bias.x, accA[r][1] + bias.y,
                                accA[r][2] + bias.z, accA[r][3] + bias.w);
        float4 v1 = make_float4(accB[r][0] + bias.x, accB[r][1] + bias.y,
                                accB[r][2] + bias.z, accB[r][3] + bias.w);
        *(float4*)&out[(size_t)m * kC + n0 + ty * 4] = v0;
        *(float4*)&out[(size_t)(m + 64) * kC + n0 + ty * 4] = v1;
    }
}

// ---------------------------------------------------------------------------
// Host launcher.
// Workspace plan (one "plane" = kM floats = 128 KiB):
//   ws:  qkv 576 | offb 18 | kd 64 | vd 64 | ao 192  = 914 planes
//   appended: dwtb2,dwtb3 bf16 (36864 each = 0.28 plane each)
//   total = 119,947,264 B < round-3's proven-fitting 120,094,720 B.
// Aliased into ao (all consumed before their region is overwritten):
//   xb    planes 0..95    (consumed by qkv_mfma; attn0 writes 0..63 after)
//   qwb   planes 160..161 (consumed by qkv_mfma)
//   kpx   planes 128..159 (written by repack_px, consumed by deform_mfma;
//                          attn2 writes 128..191 only after deform#2)
//   vpx   planes 160..191 (same; overlays dead qwb)
// Stream order guarantees every consumer runs before the region's next writer.
// ---------------------------------------------------------------------------
extern "C" void kernel_launch(void* const* d_in, const int* in_sizes, int n_in,
                              void* d_out, int out_size, void* d_ws, size_t ws_size,
                              hipStream_t stream) {
    const float* x      = (const float*)d_in[0];
    const float* qkv_w  = (const float*)d_in[1];
    const float* proj_w = (const float*)d_in[2];
    const float* proj_b = (const float*)d_in[3];
    const float* off_w2 = (const float*)d_in[4];
    const float* off_b2 = (const float*)d_in[5];
    const float* def_w2 = (const float*)d_in[6];
    const float* def_b2 = (const float*)d_in[7];
    const float* off_w3 = (const float*)d_in[8];
    const float* off_b3 = (const float*)d_in[9];
    const float* def_w3 = (const float*)d_in[10];
    const float* def_b3 = (const float*)d_in[11];
    float* out = (float*)d_out;

    float* ws   = (float*)d_ws;
    float* qkv  = ws;                               // 576 * M  fp32 planar
    float* offb = qkv + (size_t)kNQKV * kM;         // 18 * M
    float* kd   = offb + (size_t)18 * kM;           // 64 * M
    float* vd   = kd + (size_t)kD * kM;             // 64 * M
    float* ao   = vd + (size_t)kD * kM;             // 192 * M
    ushort_t* dwtb2 = (ushort_t*)(ao + (size_t)192 * kM);     // appended
    ushort_t* dwtb3 = dwtb2 + kD * kD * 9;
    // bf16 staging aliased INTO ao (see plan above)
    ushort_t* xb    = (ushort_t*)ao;                          // planes 0..95
    ushort_t* qwb   = (ushort_t*)(ao + (size_t)160 * kM);     // planes 160..161
    ushort_t* kpx   = (ushort_t*)(ao + (size_t)128 * kM);     // planes 128..159
    ushort_t* vpx   = (ushort_t*)(ao + (size_t)160 * kM);     // planes 160..191

    // 0. bf16 conversions (x, qkv_w) and deform-weight transposes
    cvt_bf16<<<(kM * kC / 2 + 255) / 256, 256, 0, stream>>>(x, (unsigned*)xb, kM * kC / 2);
    cvt_bf16<<<(kNQKV * kC / 2 + 255) / 256, 256, 0, stream>>>(qkv_w, (unsigned*)qwb, kNQKV * kC / 2);
    dw_tb<<<144, 256, 0, stream>>>(def_w2, dwtb2);
    dw_tb<<<144, 256, 0, stream>>>(def_w3, dwtb3);

    // 1. QKV projection (bf16 MFMA) — consumes xb, qwb
    qkv_mfma<<<dim3(kM / 64, kNQKV / 64), 256, 0, stream>>>(xb, qwb, qkv);

    // 2. branch 0 (dil=1) — attn0 overwrites ao planes 0..63 (xb region, dead)
    attn_kernel<<<kB * kH, 512, 0, stream>>>(
        qkv, qkv + (size_t)kC * kHW, qkv + (size_t)2 * kC * kHW, ao,
        0, 1, kNQKV * kHW);

    // 3. branch 1 (dil=2)
    off_conv<<<kB * 18 * 16, 256, 0, stream>>>(qkv, off_w2, off_b2, offb, 1, 2);
    repack_px<<<256, 256, 0, stream>>>(
        qkv + (size_t)(kC + 1 * kD) * kHW, qkv + (size_t)(2 * kC + 1 * kD) * kHW,
        kpx, vpx, kNQKV * kHW);
    deform_mfma<<<1024, 256, 0, stream>>>(kpx, vpx, offb, dwtb2, def_b2, kd, vd, 2);
    attn_kernel<<<kB * kH, 512, 0, stream>>>(qkv, kd, vd, ao, 1, 2, kD * kHW);

    // 4. branch 2 (dil=3)
    off_conv<<<kB * 18 * 16, 256, 0, stream>>>(qkv, off_w3, off_b3, offb, 2, 3);
    repack_px<<<256, 256, 0, stream>>>(
        qkv + (size_t)(kC + 2 * kD) * kHW, qkv + (size_t)(2 * kC + 2 * kD) * kHW,
        kpx, vpx, kNQKV * kHW);
    deform_mfma<<<1024, 256, 0, stream>>>(kpx, vpx, offb, dwtb3, def_b3, kd, vd, 3);
    attn_kernel<<<kB * kH, 512, 0, stream>>>(qkv, kd, vd, ao, 2, 3, kD * kHW);

    // 5. output projection (fp32)
    proj_gemm<<<dim3(kM / 128, kC / 64), 256, 0, stream>>>(ao, proj_w, proj_b, out);
}

// Round 8
// 466.417 us; speedup vs baseline: 2.3838x; 1.1979x over previous
//
#include <hip/hip_runtime.h>
#include <cmath>

// ---------------------------------------------------------------------------
// Problem constants (B=8, H=W=64, C=192, 3 dilation branches of d=64, heads=64)
// ---------------------------------------------------------------------------
#define kB    8
#define kH    64
#define kW    64
#define kHW   4096          // H*W
#define kC    192
#define kD    64            // channels per dilation branch == head_dim
#define kM    (kB * kHW)    // 32768 total pixels
#define kNQKV 576           // 3*C

typedef unsigned short ushort_t;
typedef __attribute__((ext_vector_type(8))) short  s8v;   // 8 bf16 (4 VGPRs)
typedef __attribute__((ext_vector_type(4))) float  f4v;   // MFMA C/D frag

__device__ inline unsigned short bf16r(float f) {   // round-to-nearest-even
    union { float f; unsigned u; } v; v.f = f;
    unsigned u = v.u + 0x7FFFu + ((v.u >> 16) & 1u);
    return (unsigned short)(u >> 16);
}
__device__ inline float bfu(short s) {              // bf16 -> fp32
    union { unsigned u; float f; } v;
    v.u = ((unsigned)(unsigned short)s) << 16;
    return v.f;
}

// ---------------------------------------------------------------------------
// fp32 -> bf16 pairwise converter (dst as packed uint = 2 bf16)
// ---------------------------------------------------------------------------
__global__ void cvt_bf16(const float* __restrict__ src, unsigned* __restrict__ dst, int n2) {
    int i = blockIdx.x * 256 + threadIdx.x;
    if (i >= n2) return;
    float2 f = ((const float2*)src)[i];
    dst[i] = (unsigned)bf16r(f.x) | ((unsigned)bf16r(f.y) << 16);
}

// ---------------------------------------------------------------------------
// deform weights: dw (o,c,kk) fp32 -> dwtb[kk][o][c] bf16
// ---------------------------------------------------------------------------
__global__ void dw_tb(const float* __restrict__ dw, ushort_t* __restrict__ dwtb) {
    int l = blockIdx.x * 256 + threadIdx.x;   // 64*64*9 = 36864
    if (l >= kD * kD * 9) return;
    int o = l / 576;
    int c = (l / 9) % 64;
    int kk = l % 9;
    dwtb[(kk * 64 + o) * 64 + c] = bf16r(dw[l]);
}

// ---------------------------------------------------------------------------
// offset-conv weights: ow (18, 64, 3, 3) fp32 -> owtb[kk][n=32 pad][c=64] bf16
// (n >= 18 zero-padded so the MFMA N-dimension is clean)
// ---------------------------------------------------------------------------
__global__ void ow_tb(const float* __restrict__ ow, ushort_t* __restrict__ owtb) {
    int l = blockIdx.x * 256 + threadIdx.x;   // 9*32*64 = 18432
    if (l >= 9 * 32 * 64) return;
    int kk = l >> 11;          // /2048
    int j  = (l >> 6) & 31;
    int c  = l & 63;
    owtb[l] = (j < 18) ? bf16r(ow[j * 576 + c * 9 + kk]) : (ushort_t)0;
}

// ---------------------------------------------------------------------------
// Repack: fp32 planar (64ch) -> bf16 pixel-major [b][p][c] for k AND v.
// ---------------------------------------------------------------------------
__global__ __launch_bounds__(256) void repack_px(const float* __restrict__ kbase,
                                                 const float* __restrict__ vbase,
                                                 ushort_t* __restrict__ kpx,
                                                 ushort_t* __restrict__ vpx,
                                                 int bstride) {
    const int t  = blockIdx.x >> 7;           // 0=k, 1=v
    const int b  = (blockIdx.x >> 4) & 7;
    const int p  = (blockIdx.x & 15) * 256 + threadIdx.x;
    const float* in = (t ? vbase : kbase) + (size_t)b * bstride + p;
    ushort_t* outp = (t ? vpx : kpx) + ((size_t)b * kHW + p) * 64;
    unsigned buf[32];
#pragma unroll
    for (int c = 0; c < 32; ++c) {
        float f0 = in[(size_t)(2 * c) * kHW];
        float f1 = in[(size_t)(2 * c + 1) * kHW];
        buf[c] = (unsigned)bf16r(f0) | ((unsigned)bf16r(f1) << 16);
    }
#pragma unroll
    for (int i = 0; i < 8; ++i)
        ((uint4*)outp)[i] = make_uint4(buf[i * 4], buf[i * 4 + 1], buf[i * 4 + 2], buf[i * 4 + 3]);
}

// ---------------------------------------------------------------------------
// Kernel 1: QKV projection via bf16 MFMA, LDS-free.
// ---------------------------------------------------------------------------
__global__ __launch_bounds__(256) void qkv_mfma(const ushort_t* __restrict__ xb,
                                                const ushort_t* __restrict__ qwb,
                                                float* __restrict__ qkv) {
    const int tid  = threadIdx.x;
    const int lane = tid & 63;
    const int wave = tid >> 6;
    const int l15  = lane & 15;
    const int q    = lane >> 4;
    const int m0   = blockIdx.x * 64 + wave * 16;
    const int n0   = blockIdx.y * 64;

    f4v acc[4];
#pragma unroll
    for (int ob = 0; ob < 4; ++ob) acc[ob] = (f4v){0.f, 0.f, 0.f, 0.f};

    const ushort_t* ap = xb + (size_t)(m0 + l15) * kC + q * 8;
#pragma unroll
    for (int kc = 0; kc < 6; ++kc) {
        s8v a = *(const s8v*)(ap + kc * 32);
#pragma unroll
        for (int ob = 0; ob < 4; ++ob) {
            s8v b = *(const s8v*)(qwb + (size_t)(n0 + ob * 16 + l15) * kC + kc * 32 + q * 8);
            acc[ob] = __builtin_amdgcn_mfma_f32_16x16x32_bf16(a, b, acc[ob], 0, 0, 0);
        }
    }
    const int b_img = m0 >> 12;
    const int p = (m0 & 4095) + q * 4;   // D row = q*4 + reg
#pragma unroll
    for (int ob = 0; ob < 4; ++ob) {
        int n = n0 + ob * 16 + l15;      // D col = lane&15
        *(f4v*)&qkv[(size_t)(b_img * kNQKV + n) * kHW + p] = acc[ob];
    }
}

// ---------------------------------------------------------------------------
// Kernel 2: offsets conv via bf16 MFMA over pixel-major k (kpx).
// 3x3 dilated conv 64 -> 18 (padded to 32) channels. One block per (b,row),
// 4 waves x 16 px. Per tap: A = shifted pixel's 64 channels (2 x 16B loads,
// zeroed if OOB — integral shifts, zero-pad semantics), B = owtb[kk][n][c]
// (L1-resident), 4 MFMAs. Replaces the scalar version that issued 576
// scalar loads/thread and re-read inputs 18x (VALUBusy 48%, 70.7 us).
// ---------------------------------------------------------------------------
__global__ __launch_bounds__(256) void off_conv_mfma(const ushort_t* __restrict__ kpx,
                                                     const ushort_t* __restrict__ owtb,
                                                     const float* __restrict__ obias,
                                                     float* __restrict__ offb,
                                                     int dil) {
    const int lb = (blockIdx.x & 7) * 64 + (blockIdx.x >> 3);   // XCD swizzle (G=512)
    const int b = lb >> 6;
    const int y = lb & 63;
    const int tid  = threadIdx.x;
    const int lane = tid & 63;
    const int wave = tid >> 6;
    const int l15  = lane & 15;
    const int q    = lane >> 4;
    const int px   = wave * 16 + l15;

    const ushort_t* inpx = kpx + (size_t)b * kHW * 64 + q * 8;

    f4v acc[2];
    acc[0] = (f4v){0.f, 0.f, 0.f, 0.f};
    acc[1] = (f4v){0.f, 0.f, 0.f, 0.f};

#pragma unroll
    for (int kk = 0; kk < 9; ++kk) {
        const int yy = y + (kk / 3 - 1) * dil;
        const int xx = px + (kk % 3 - 1) * dil;
        const bool valid = (yy >= 0) & (yy < kH) & (xx >= 0) & (xx < kW);
        const size_t idx = valid ? (size_t)(yy * kW + xx) * 64 : 0;
        s8v a0 = *(const s8v*)(inpx + idx);
        s8v a1 = *(const s8v*)(inpx + idx + 32);
        if (!valid) {
            a0 = (s8v){0, 0, 0, 0, 0, 0, 0, 0};
            a1 = (s8v){0, 0, 0, 0, 0, 0, 0, 0};
        }
        const ushort_t* wb = owtb + (size_t)kk * 2048 + l15 * 64 + q * 8;
#pragma unroll
        for (int nb = 0; nb < 2; ++nb) {
            s8v b0 = *(const s8v*)(wb + nb * 1024);
            s8v b1 = *(const s8v*)(wb + nb * 1024 + 32);
            acc[nb] = __builtin_amdgcn_mfma_f32_16x16x32_bf16(a0, b0, acc[nb], 0, 0, 0);
            acc[nb] = __builtin_amdgcn_mfma_f32_16x16x32_bf16(a1, b1, acc[nb], 0, 0, 0);
        }
    }
#pragma unroll
    for (int nb = 0; nb < 2; ++nb) {
        int n = nb * 16 + l15;               // D col = output channel
        if (n < 18) {
            float bias = obias[n];
            f4v v = acc[nb];
            v.x += bias; v.y += bias; v.z += bias; v.w += bias;
            // D rows = pixels wave*16 + q*4 + reg
            *(f4v*)&offb[((size_t)b * 18 + n) * kHW + y * kW + wave * 16 + q * 4] = v;
        }
    }
}

// ---------------------------------------------------------------------------
// Kernel 3: deformable 3x3 conv via bf16 MFMA on pixel-major input.
// ---------------------------------------------------------------------------
__global__ __launch_bounds__(256) void deform_mfma(const ushort_t* __restrict__ kpx,
                                                   const ushort_t* __restrict__ vpx,
                                                   const float* __restrict__ offb,
                                                   const ushort_t* __restrict__ dwtb,
                                                   const float* __restrict__ db,
                                                   float* __restrict__ outk,
                                                   float* __restrict__ outv,
                                                   int dil) {
    const int lb = (blockIdx.x & 7) * 128 + (blockIdx.x >> 3);  // XCD swizzle (G=1024)
    const int t = lb >> 9;          // 0 = k, 1 = v
    const int b = (lb >> 6) & 7;
    const int y = lb & 63;
    const int tid  = threadIdx.x;
    const int lane = tid & 63;
    const int wave = tid >> 6;
    const int l15  = lane & 15;
    const int q    = lane >> 4;
    const int px   = wave * 16 + l15;   // A-operand pixel for this lane

    const ushort_t* inpx = (t ? vpx : kpx) + (size_t)b * kHW * 64 + q * 8;
    float* outp = t ? outv : outk;

    f4v acc[4];
#pragma unroll
    for (int ob = 0; ob < 4; ++ob) acc[ob] = (f4v){0.f, 0.f, 0.f, 0.f};

    const float* offrow = offb + (size_t)b * 18 * kHW + y * kW + px;

    for (int kk = 0; kk < 9; ++kk) {
        // --- bilinear coords for my pixel (registers only) ---
        float oy = offrow[(size_t)(kk * 2 + 0) * kHW];
        float ox = offrow[(size_t)(kk * 2 + 1) * kHW];
        float py = (float)y + (float)((kk / 3 - 1) * dil) + oy;
        float pxf = (float)px + (float)((kk % 3 - 1) * dil) + ox;
        float fy = floorf(py), fx = floorf(pxf);
        float wy = py - fy, wx = pxf - fx;
        int y0 = (int)fy, x0 = (int)fx;
        int y1 = y0 + 1, x1 = x0 + 1;
        int y0c = min(max(y0, 0), kH - 1), x0c = min(max(x0, 0), kW - 1);
        int y1c = min(max(y1, 0), kH - 1), x1c = min(max(x1, 0), kW - 1);
        bool vy0 = (y0 >= 0) & (y0 < kH), vx0 = (x0 >= 0) & (x0 < kW);
        bool vy1 = (y1 >= 0) & (y1 < kH), vx1 = (x1 >= 0) & (x1 < kW);
        const size_t i00 = (size_t)(y0c * kW + x0c) * 64;
        const size_t i01 = (size_t)(y0c * kW + x1c) * 64;
        const size_t i10 = (size_t)(y1c * kW + x0c) * 64;
        const size_t i11 = (size_t)(y1c * kW + x1c) * 64;
        const float w00 = (vy0 && vx0) ? (1.f - wy) * (1.f - wx) : 0.f;
        const float w01 = (vy0 && vx1) ? (1.f - wy) * wx : 0.f;
        const float w10 = (vy1 && vx0) ? wy * (1.f - wx) : 0.f;
        const float w11 = (vy1 && vx1) ? wy * wx : 0.f;

        // --- 8 x 16B corner loads (16 contiguous channels each corner) ---
        s8v c00a = *(const s8v*)(inpx + i00);
        s8v c00b = *(const s8v*)(inpx + i00 + 32);
        s8v c01a = *(const s8v*)(inpx + i01);
        s8v c01b = *(const s8v*)(inpx + i01 + 32);
        s8v c10a = *(const s8v*)(inpx + i10);
        s8v c10b = *(const s8v*)(inpx + i10 + 32);
        s8v c11a = *(const s8v*)(inpx + i11);
        s8v c11b = *(const s8v*)(inpx + i11 + 32);

        s8v a0, a1;
#pragma unroll
        for (int j = 0; j < 8; ++j) {
            float v0 = w00 * bfu(c00a[j]) + w01 * bfu(c01a[j]) +
                       w10 * bfu(c10a[j]) + w11 * bfu(c11a[j]);
            float v1 = w00 * bfu(c00b[j]) + w01 * bfu(c01b[j]) +
                       w10 * bfu(c10b[j]) + w11 * bfu(c11b[j]);
            a0[j] = (short)bf16r(v0);
            a1[j] = (short)bf16r(v1);
        }
        // --- B-frags straight from global (dwtb[kk][o][c]) + MFMA ---
        const ushort_t* wb = dwtb + (size_t)kk * 4096 + l15 * 64 + q * 8;
#pragma unroll
        for (int ob = 0; ob < 4; ++ob) {
            s8v b0 = *(const s8v*)(wb + ob * 1024);
            s8v b1 = *(const s8v*)(wb + ob * 1024 + 32);
            acc[ob] = __builtin_amdgcn_mfma_f32_16x16x32_bf16(a0, b0, acc[ob], 0, 0, 0);
            acc[ob] = __builtin_amdgcn_mfma_f32_16x16x32_bf16(a1, b1, acc[ob], 0, 0, 0);
        }
    }
#pragma unroll
    for (int ob = 0; ob < 4; ++ob) {
        int o = ob * 16 + l15;                       // D col
        float bias = db[o];
        f4v v = acc[ob];
        v.x += bias; v.y += bias; v.z += bias; v.w += bias;
        // D rows = px = wave*16 + q*4 + reg
        *(f4v*)&outp[((size_t)(b * kD + o)) * kHW + y * kW + wave * 16 + q * 4] = v;
    }
}

// ---------------------------------------------------------------------------
// Kernel 4: 9-tap local attention, one block per (b, row), XCD-swizzled.
// ---------------------------------------------------------------------------
__global__ __launch_bounds__(512) void attn_kernel(const float* __restrict__ qkv,
                                                   const float* __restrict__ ksrc,
                                                   const float* __restrict__ vsrc,
                                                   float* __restrict__ ao,
                                                   int branch, int dil, int kvstride) {
    __shared__ float part[9][8][64];
    const int lb = (blockIdx.x & 7) * 64 + (blockIdx.x >> 3);   // XCD swizzle (G=512)
    const int tid = threadIdx.x;
    const int x = tid & 63;
    const int g = tid >> 6;          // 0..7, wave-uniform
    const int b = lb >> 6;
    const int y = lb & 63;
    const int p = y * kW + x;
    const int pg = b * kHW + p;

    const float* qb = qkv + ((size_t)b * kNQKV + branch * kD) * kHW + p;
    const float* kb = ksrc + (size_t)b * kvstride;
    const float* vb = vsrc + (size_t)b * kvstride;

    int offs[9]; float msk[9];
#pragma unroll
    for (int kk = 0; kk < 9; ++kk) {
        int dy = (kk / 3 - 1) * dil, dx = (kk % 3 - 1) * dil;
        int yy = y + dy, xx = x + dx;
        bool v = (yy >= 0) & (yy < kH) & (xx >= 0) & (xx < kW);
        offs[kk] = v ? (p + dy * kW + dx) : 0;
        msk[kk] = v ? 1.f : 0.f;
    }
    float sc[9];
#pragma unroll
    for (int kk = 0; kk < 9; ++kk) sc[kk] = 0.f;
#pragma unroll
    for (int cc = 0; cc < 8; ++cc) {
        int c = g * 8 + cc;
        float qv = qb[(size_t)c * kHW];
        const float* kp = kb + (size_t)c * kHW;
#pragma unroll
        for (int kk = 0; kk < 9; ++kk) sc[kk] += qv * (msk[kk] * kp[offs[kk]]);
    }
#pragma unroll
    for (int kk = 0; kk < 9; ++kk) part[kk][g][x] = sc[kk];
    __syncthreads();

    float e[9], mx = -1e30f;
#pragma unroll
    for (int kk = 0; kk < 9; ++kk) {
        float s = 0.f;
#pragma unroll
        for (int gg = 0; gg < 8; ++gg) s += part[kk][gg][x];
        s *= 0.125f;
        e[kk] = s;
        mx = fmaxf(mx, s);
    }
    float ssum = 0.f;
#pragma unroll
    for (int kk = 0; kk < 9; ++kk) { e[kk] = __expf(e[kk] - mx); ssum += e[kk]; }
    float inv = 1.f / ssum;
#pragma unroll
    for (int kk = 0; kk < 9; ++kk) e[kk] = e[kk] * inv * msk[kk];

#pragma unroll
    for (int cc = 0; cc < 8; ++cc) {
        int c = g * 8 + cc;
        const float* vp = vb + (size_t)c * kHW;
        float o = 0.f;
#pragma unroll
        for (int kk = 0; kk < 9; ++kk) o += e[kk] * vp[offs[kk]];
        ao[(size_t)(branch * kD + c) * kM + pg] = o;
    }
}

// ---------------------------------------------------------------------------
// Kernel 5: output projection GEMM (fp32 SIMT).  ao: (192, M) planar.
// ---------------------------------------------------------------------------
__global__ __launch_bounds__(256) void proj_gemm(const float* __restrict__ ao,
                                                 const float* __restrict__ pw,
                                                 const float* __restrict__ pb,
                                                 float* __restrict__ out) {
    __shared__ float As[32][132];   // [kk][mm]
    __shared__ float Bs[32][68];    // [kk][nn]
    const int tid = threadIdx.x;
    const int tx = tid & 15;   // m quad
    const int ty = tid >> 4;   // n quad
    const int m0 = blockIdx.x * 128;
    const int n0 = blockIdx.y * 64;

    float accA[4][4], accB[4][4];
#pragma unroll
    for (int r = 0; r < 4; ++r)
#pragma unroll
        for (int j = 0; j < 4; ++j) { accA[r][j] = 0.f; accB[r][j] = 0.f; }

    for (int k0 = 0; k0 < kC; k0 += 32) {
#pragma unroll
        for (int it = 0; it < 16; ++it) {
            int l = it * 256 + tid;
            int mm = l & 127, kk = l >> 7;
            As[kk][mm] = ao[(size_t)(k0 + kk) * kM + m0 + mm];
        }
#pragma unroll
        for (int it = 0; it < 8; ++it) {
            int l = it * 256 + tid;
            int kk = l & 31, nn = l >> 5;
            Bs[kk][nn] = pw[(size_t)(n0 + nn) * kC + k0 + kk];
        }
        __syncthreads();
#pragma unroll
        for (int kk = 0; kk < 32; ++kk) {
            float4 a0 = *(const float4*)&As[kk][tx * 4];
            float4 a1 = *(const float4*)&As[kk][64 + tx * 4];
            float4 b  = *(const float4*)&Bs[kk][ty * 4];
            const float ar0[4] = {a0.x, a0.y, a0.z, a0.w};
            const float ar1[4] = {a1.x, a1.y, a1.z, a1.w};
            const float br[4]  = {b.x, b.y, b.z, b.w};
#pragma unroll
            for (int r = 0; r < 4; ++r)
#pragma unroll
                for (int j = 0; j < 4; ++j) {
                    accA[r][j] += ar0[r] * br[j];
                    accB[r][j] += ar1[r] * br[j];
                }
        }
        __syncthreads();
    }
    float4 bias = *(const float4*)&pb[n0 + ty * 4];
#pragma unroll
    for (int r = 0; r < 4; ++r) {
        int m = m0 + tx * 4 + r;
        float4 v0 = make_float4(accA[r][0] + bias.x, accA[r][1] + bias.y,
                                accA[r][2] + bias.z, accA[r][3] + bias.w);
        float4 v1 = make_float4(accB[r][0] + bias.x, accB[r][1] + bias.y,
                                accB[r][2] + bias.z, accB[r][3] + bias.w);
        *(float4*)&out[(size_t)m * kC + n0 + ty * 4] = v0;
        *(float4*)&out[(size_t)(m + 64) * kC + n0 + ty * 4] = v1;
    }
}

// ---------------------------------------------------------------------------
// Host launcher.
// Workspace plan (one "plane" = kM floats = 128 KiB):
//   ws:  qkv 576 | offb 18 | kd 64 | vd 64 | ao 192  = 914 planes
//   appended: dwtb2,dwtb3 (36864 bf16 each) + owtb2,owtb3 (18432 bf16 each)
//   total = 120,020,992 B  <= round-3's proven-fitting 120,094,720 B.
// Aliased into ao (all consumed before their region is overwritten):
//   xb    planes 0..95    (consumed by qkv_mfma; attn0 writes 0..63 after)
//   qwb   planes 160..161 (consumed by qkv_mfma)
//   kpx   planes 128..159 (repack_px -> off_conv_mfma + deform_mfma;
//                          attn2 writes 128..191 only after deform#2)
//   vpx   planes 160..191 (same; overlays dead qwb)
// ---------------------------------------------------------------------------
extern "C" void kernel_launch(void* const* d_in, const int* in_sizes, int n_in,
                              void* d_out, int out_size, void* d_ws, size_t ws_size,
                              hipStream_t stream) {
    const float* x      = (const float*)d_in[0];
    const float* qkv_w  = (const float*)d_in[1];
    const float* proj_w = (const float*)d_in[2];
    const float* proj_b = (const float*)d_in[3];
    const float* off_w2 = (const float*)d_in[4];
    const float* off_b2 = (const float*)d_in[5];
    const float* def_w2 = (const float*)d_in[6];
    const float* def_b2 = (const float*)d_in[7];
    const float* off_w3 = (const float*)d_in[8];
    const float* off_b3 = (const float*)d_in[9];
    const float* def_w3 = (const float*)d_in[10];
    const float* def_b3 = (const float*)d_in[11];
    float* out = (float*)d_out;

    float* ws   = (float*)d_ws;
    float* qkv  = ws;                               // 576 * M  fp32 planar
    float* offb = qkv + (size_t)kNQKV * kM;         // 18 * M
    float* kd   = offb + (size_t)18 * kM;           // 64 * M
    float* vd   = kd + (size_t)kD * kM;             // 64 * M
    float* ao   = vd + (size_t)kD * kM;             // 192 * M
    ushort_t* dwtb2 = (ushort_t*)(ao + (size_t)192 * kM);     // appended
    ushort_t* dwtb3 = dwtb2 + kD * kD * 9;
    ushort_t* owtb2 = dwtb3 + kD * kD * 9;
    ushort_t* owtb3 = owtb2 + 9 * 32 * 64;
    // bf16 staging aliased INTO ao (see plan above)
    ushort_t* xb    = (ushort_t*)ao;                          // planes 0..95
    ushort_t* qwb   = (ushort_t*)(ao + (size_t)160 * kM);     // planes 160..161
    ushort_t* kpx   = (ushort_t*)(ao + (size_t)128 * kM);     // planes 128..159
    ushort_t* vpx   = (ushort_t*)(ao + (size_t)160 * kM);     // planes 160..191

    // 0. bf16 conversions and weight transposes
    cvt_bf16<<<(kM * kC / 2 + 255) / 256, 256, 0, stream>>>(x, (unsigned*)xb, kM * kC / 2);
    cvt_bf16<<<(kNQKV * kC / 2 + 255) / 256, 256, 0, stream>>>(qkv_w, (unsigned*)qwb, kNQKV * kC / 2);
    dw_tb<<<144, 256, 0, stream>>>(def_w2, dwtb2);
    dw_tb<<<144, 256, 0, stream>>>(def_w3, dwtb3);
    ow_tb<<<72, 256, 0, stream>>>(off_w2, owtb2);
    ow_tb<<<72, 256, 0, stream>>>(off_w3, owtb3);

    // 1. QKV projection (bf16 MFMA) — consumes xb, qwb
    qkv_mfma<<<dim3(kM / 64, kNQKV / 64), 256, 0, stream>>>(xb, qwb, qkv);

    // 2. branch 0 (dil=1) — attn0 overwrites ao planes 0..63 (xb region, dead)
    attn_kernel<<<kB * kH, 512, 0, stream>>>(
        qkv, qkv + (size_t)kC * kHW, qkv + (size_t)2 * kC * kHW, ao,
        0, 1, kNQKV * kHW);

    // 3. branch 1 (dil=2): repack -> offsets (MFMA on kpx) -> deform -> attn
    repack_px<<<256, 256, 0, stream>>>(
        qkv + (size_t)(kC + 1 * kD) * kHW, qkv + (size_t)(2 * kC + 1 * kD) * kHW,
        kpx, vpx, kNQKV * kHW);
    off_conv_mfma<<<512, 256, 0, stream>>>(kpx, owtb2, off_b2, offb, 2);
    deform_mfma<<<1024, 256, 0, stream>>>(kpx, vpx, offb, dwtb2, def_b2, kd, vd, 2);
    attn_kernel<<<kB * kH, 512, 0, stream>>>(qkv, kd, vd, ao, 1, 2, kD * kHW);

    // 4. branch 2 (dil=3)
    repack_px<<<256, 256, 0, stream>>>(
        qkv + (size_t)(kC + 2 * kD) * kHW, qkv + (size_t)(2 * kC + 2 * kD) * kHW,
        kpx, vpx, kNQKV * kHW);
    off_conv_mfma<<<512, 256, 0, stream>>>(kpx, owtb3, off_b3, offb, 3);
    deform_mfma<<<1024, 256, 0, stream>>>(kpx, vpx, offb, dwtb3, def_b3, kd, vd, 3);
    attn_kernel<<<kB * kH, 512, 0, stream>>>(qkv, kd, vd, ao, 2, 3, kD * kHW);

    // 5. output projection (fp32)
    proj_gemm<<<dim3(kM / 128, kC / 64), 256, 0, stream>>>(ao, proj_w, proj_b, out);
}

// Round 9
// 389.571 us; speedup vs baseline: 2.8540x; 1.1973x over previous
//
#include <hip/hip_runtime.h>
#include <cmath>

// ---------------------------------------------------------------------------
// Problem constants (B=8, H=W=64, C=192, 3 dilation branches of d=64, heads=64)
// ---------------------------------------------------------------------------
#define kB    8
#define kH    64
#define kW    64
#define kHW   4096          // H*W
#define kC    192
#define kD    64            // channels per dilation branch == head_dim
#define kM    (kB * kHW)    // 32768 total pixels
#define kNQKV 576           // 3*C

typedef unsigned short ushort_t;
typedef __attribute__((ext_vector_type(8))) short  s8v;   // 8 bf16 (4 VGPRs)
typedef __attribute__((ext_vector_type(4))) float  f4v;   // MFMA C/D frag

__device__ inline unsigned short bf16r(float f) {   // round-to-nearest-even
    union { float f; unsigned u; } v; v.f = f;
    unsigned u = v.u + 0x7FFFu + ((v.u >> 16) & 1u);
    return (unsigned short)(u >> 16);
}
__device__ inline float bfu(short s) {              // bf16 -> fp32
    union { unsigned u; float f; } v;
    v.u = ((unsigned)(unsigned short)s) << 16;
    return v.f;
}

// ---------------------------------------------------------------------------
// fp32 -> bf16 pairwise converter
// ---------------------------------------------------------------------------
__global__ void cvt_bf16(const float* __restrict__ src, unsigned* __restrict__ dst, int n2) {
    int i = blockIdx.x * 256 + threadIdx.x;
    if (i >= n2) return;
    float2 f = ((const float2*)src)[i];
    dst[i] = (unsigned)bf16r(f.x) | ((unsigned)bf16r(f.y) << 16);
}

// ---------------------------------------------------------------------------
// deform weights: dw (o,c,kk) fp32 -> dwtb[kk][o][c] bf16
// ---------------------------------------------------------------------------
__global__ void dw_tb(const float* __restrict__ dw, ushort_t* __restrict__ dwtb) {
    int l = blockIdx.x * 256 + threadIdx.x;   // 64*64*9 = 36864
    if (l >= kD * kD * 9) return;
    int o = l / 576;
    int c = (l / 9) % 64;
    int kk = l % 9;
    dwtb[(kk * 64 + o) * 64 + c] = bf16r(dw[l]);
}

// ---------------------------------------------------------------------------
// offset-conv weights: ow (18,64,3,3) fp32 -> owtb[kk][n=32 pad][c=64] bf16
// ---------------------------------------------------------------------------
__global__ void ow_tb(const float* __restrict__ ow, ushort_t* __restrict__ owtb) {
    int l = blockIdx.x * 256 + threadIdx.x;   // 9*32*64 = 18432
    if (l >= 9 * 32 * 64) return;
    int kk = l >> 11;
    int j  = (l >> 6) & 31;
    int c  = l & 63;
    owtb[l] = (j < 18) ? bf16r(ow[j * 576 + c * 9 + kk]) : (ushort_t)0;
}

// ---------------------------------------------------------------------------
// Repack: fp32 planar (64ch) -> bf16 pixel-major [b][p][c]  (deform outputs)
// ---------------------------------------------------------------------------
__global__ __launch_bounds__(256) void repack_px(const float* __restrict__ kbase,
                                                 const float* __restrict__ vbase,
                                                 ushort_t* __restrict__ kpx,
                                                 ushort_t* __restrict__ vpx,
                                                 int bstride) {
    const int t  = blockIdx.x >> 7;           // 0=k, 1=v
    const int b  = (blockIdx.x >> 4) & 7;
    const int p  = (blockIdx.x & 15) * 256 + threadIdx.x;
    const float* in = (t ? vbase : kbase) + (size_t)b * bstride + p;
    ushort_t* outp = (t ? vpx : kpx) + ((size_t)b * kHW + p) * 64;
    unsigned buf[32];
#pragma unroll
    for (int c = 0; c < 32; ++c) {
        float f0 = in[(size_t)(2 * c) * kHW];
        float f1 = in[(size_t)(2 * c + 1) * kHW];
        buf[c] = (unsigned)bf16r(f0) | ((unsigned)bf16r(f1) << 16);
    }
#pragma unroll
    for (int i = 0; i < 8; ++i)
        ((uint4*)outp)[i] = make_uint4(buf[i * 4], buf[i * 4 + 1], buf[i * 4 + 2], buf[i * 4 + 3]);
}

// ---------------------------------------------------------------------------
// Kernel 1: QKV projection, MFMA, output bf16 PIXEL-MAJOR per tensor.
// D row (q*4+reg) = A-row = qkv channel; D col (lane&15) = B-row = pixel
// (operand-role swap vs round 8: fixes the scattered fp32 planar stores that
// made qkv store-bound at 70 us / 1.1 TB/s effective).
// blockIdx.y = tensor 0..8 (q0,q1,q2,k0,k1,k2,v0,v1,v2), each [b][p][64] bf16.
// Wave = 16 ch x 64 px; block = 64 ch x 64 px.
// ---------------------------------------------------------------------------
__global__ __launch_bounds__(256) void qkv_mfma2(const ushort_t* __restrict__ xb,
                                                 const ushort_t* __restrict__ qwb,
                                                 ushort_t* __restrict__ qkvpx) {
    const int tid  = threadIdx.x;
    const int lane = tid & 63;
    const int wave = tid >> 6;
    const int l15  = lane & 15;
    const int q    = lane >> 4;
    const int m0   = blockIdx.x * 64;
    const int ty   = blockIdx.y;                 // tensor index
    const int nb   = ty * 64 + wave * 16;        // global qkv channel strip

    f4v acc[4];
#pragma unroll
    for (int ob = 0; ob < 4; ++ob) acc[ob] = (f4v){0.f, 0.f, 0.f, 0.f};

    const ushort_t* aw = qwb + (size_t)(nb + l15) * kC + q * 8;   // A: weight rows
    const ushort_t* bx = xb + (size_t)(m0 + l15) * kC + q * 8;    // B: pixel rows
#pragma unroll
    for (int kc = 0; kc < 6; ++kc) {
        s8v a = *(const s8v*)(aw + kc * 32);
#pragma unroll
        for (int ob = 0; ob < 4; ++ob) {
            s8v b = *(const s8v*)(bx + (size_t)(ob * 16) * kC + kc * 32);
            acc[ob] = __builtin_amdgcn_mfma_f32_16x16x32_bf16(a, b, acc[ob], 0, 0, 0);
        }
    }
    // store: lane holds channels nb%64 + q*4..+3 (within tensor) at pixel ob*16+l15
    ushort_t* obase = qkvpx + (size_t)ty * kM * 64 + (size_t)m0 * 64 + wave * 16 + q * 4;
#pragma unroll
    for (int ob = 0; ob < 4; ++ob) {
        f4v v = acc[ob];
        uint2 u;
        u.x = (unsigned)bf16r(v.x) | ((unsigned)bf16r(v.y) << 16);
        u.y = (unsigned)bf16r(v.z) | ((unsigned)bf16r(v.w) << 16);
        *(uint2*)(obase + (size_t)(ob * 16 + l15) * 64) = u;
    }
}

// ---------------------------------------------------------------------------
// Kernel 2: offsets conv via bf16 MFMA over pixel-major k.
// ---------------------------------------------------------------------------
__global__ __launch_bounds__(256) void off_conv_mfma(const ushort_t* __restrict__ kpx,
                                                     const ushort_t* __restrict__ owtb,
                                                     const float* __restrict__ obias,
                                                     float* __restrict__ offb,
                                                     int dil) {
    const int lb = (blockIdx.x & 7) * 64 + (blockIdx.x >> 3);   // XCD swizzle (G=512)
    const int b = lb >> 6;
    const int y = lb & 63;
    const int tid  = threadIdx.x;
    const int lane = tid & 63;
    const int wave = tid >> 6;
    const int l15  = lane & 15;
    const int q    = lane >> 4;
    const int px   = wave * 16 + l15;

    const ushort_t* inpx = kpx + (size_t)b * kHW * 64 + q * 8;

    f4v acc[2];
    acc[0] = (f4v){0.f, 0.f, 0.f, 0.f};
    acc[1] = (f4v){0.f, 0.f, 0.f, 0.f};

#pragma unroll
    for (int kk = 0; kk < 9; ++kk) {
        const int yy = y + (kk / 3 - 1) * dil;
        const int xx = px + (kk % 3 - 1) * dil;
        const bool valid = (yy >= 0) & (yy < kH) & (xx >= 0) & (xx < kW);
        const size_t idx = valid ? (size_t)(yy * kW + xx) * 64 : 0;
        s8v a0 = *(const s8v*)(inpx + idx);
        s8v a1 = *(const s8v*)(inpx + idx + 32);
        if (!valid) {
            a0 = (s8v){0, 0, 0, 0, 0, 0, 0, 0};
            a1 = (s8v){0, 0, 0, 0, 0, 0, 0, 0};
        }
        const ushort_t* wb = owtb + (size_t)kk * 2048 + l15 * 64 + q * 8;
#pragma unroll
        for (int nbk = 0; nbk < 2; ++nbk) {
            s8v b0 = *(const s8v*)(wb + nbk * 1024);
            s8v b1 = *(const s8v*)(wb + nbk * 1024 + 32);
            acc[nbk] = __builtin_amdgcn_mfma_f32_16x16x32_bf16(a0, b0, acc[nbk], 0, 0, 0);
            acc[nbk] = __builtin_amdgcn_mfma_f32_16x16x32_bf16(a1, b1, acc[nbk], 0, 0, 0);
        }
    }
#pragma unroll
    for (int nbk = 0; nbk < 2; ++nbk) {
        int n = nbk * 16 + l15;
        if (n < 18) {
            float bias = obias[n];
            f4v v = acc[nbk];
            v.x += bias; v.y += bias; v.z += bias; v.w += bias;
            *(f4v*)&offb[((size_t)b * 18 + n) * kHW + y * kW + wave * 16 + q * 4] = v;
        }
    }
}

// ---------------------------------------------------------------------------
// Kernel 3: deformable 3x3 conv via bf16 MFMA on pixel-major input.
// Output fp32 planar (repacked to pixel-major afterwards).
// ---------------------------------------------------------------------------
__global__ __launch_bounds__(256) void deform_mfma(const ushort_t* __restrict__ kpx,
                                                   const ushort_t* __restrict__ vpx,
                                                   const float* __restrict__ offb,
                                                   const ushort_t* __restrict__ dwtb,
                                                   const float* __restrict__ db,
                                                   float* __restrict__ outk,
                                                   float* __restrict__ outv,
                                                   int dil) {
    const int lb = (blockIdx.x & 7) * 128 + (blockIdx.x >> 3);  // XCD swizzle (G=1024)
    const int t = lb >> 9;          // 0 = k, 1 = v
    const int b = (lb >> 6) & 7;
    const int y = lb & 63;
    const int tid  = threadIdx.x;
    const int lane = tid & 63;
    const int wave = tid >> 6;
    const int l15  = lane & 15;
    const int q    = lane >> 4;
    const int px   = wave * 16 + l15;

    const ushort_t* inpx = (t ? vpx : kpx) + (size_t)b * kHW * 64 + q * 8;
    float* outp = t ? outv : outk;

    f4v acc[4];
#pragma unroll
    for (int ob = 0; ob < 4; ++ob) acc[ob] = (f4v){0.f, 0.f, 0.f, 0.f};

    const float* offrow = offb + (size_t)b * 18 * kHW + y * kW + px;

    for (int kk = 0; kk < 9; ++kk) {
        float oy = offrow[(size_t)(kk * 2 + 0) * kHW];
        float ox = offrow[(size_t)(kk * 2 + 1) * kHW];
        float py = (float)y + (float)((kk / 3 - 1) * dil) + oy;
        float pxf = (float)px + (float)((kk % 3 - 1) * dil) + ox;
        float fy = floorf(py), fx = floorf(pxf);
        float wy = py - fy, wx = pxf - fx;
        int y0 = (int)fy, x0 = (int)fx;
        int y1 = y0 + 1, x1 = x0 + 1;
        int y0c = min(max(y0, 0), kH - 1), x0c = min(max(x0, 0), kW - 1);
        int y1c = min(max(y1, 0), kH - 1), x1c = min(max(x1, 0), kW - 1);
        bool vy0 = (y0 >= 0) & (y0 < kH), vx0 = (x0 >= 0) & (x0 < kW);
        bool vy1 = (y1 >= 0) & (y1 < kH), vx1 = (x1 >= 0) & (x1 < kW);
        const size_t i00 = (size_t)(y0c * kW + x0c) * 64;
        const size_t i01 = (size_t)(y0c * kW + x1c) * 64;
        const size_t i10 = (size_t)(y1c * kW + x0c) * 64;
        const size_t i11 = (size_t)(y1c * kW + x1c) * 64;
        const float w00 = (vy0 && vx0) ? (1.f - wy) * (1.f - wx) : 0.f;
        const float w01 = (vy0 && vx1) ? (1.f - wy) * wx : 0.f;
        const float w10 = (vy1 && vx0) ? wy * (1.f - wx) : 0.f;
        const float w11 = (vy1 && vx1) ? wy * wx : 0.f;

        s8v c00a = *(const s8v*)(inpx + i00);
        s8v c00b = *(const s8v*)(inpx + i00 + 32);
        s8v c01a = *(const s8v*)(inpx + i01);
        s8v c01b = *(const s8v*)(inpx + i01 + 32);
        s8v c10a = *(const s8v*)(inpx + i10);
        s8v c10b = *(const s8v*)(inpx + i10 + 32);
        s8v c11a = *(const s8v*)(inpx + i11);
        s8v c11b = *(const s8v*)(inpx + i11 + 32);

        s8v a0, a1;
#pragma unroll
        for (int j = 0; j < 8; ++j) {
            float v0 = w00 * bfu(c00a[j]) + w01 * bfu(c01a[j]) +
                       w10 * bfu(c10a[j]) + w11 * bfu(c11a[j]);
            float v1 = w00 * bfu(c00b[j]) + w01 * bfu(c01b[j]) +
                       w10 * bfu(c10b[j]) + w11 * bfu(c11b[j]);
            a0[j] = (short)bf16r(v0);
            a1[j] = (short)bf16r(v1);
        }
        const ushort_t* wb = dwtb + (size_t)kk * 4096 + l15 * 64 + q * 8;
#pragma unroll
        for (int ob = 0; ob < 4; ++ob) {
            s8v b0 = *(const s8v*)(wb + ob * 1024);
            s8v b1 = *(const s8v*)(wb + ob * 1024 + 32);
            acc[ob] = __builtin_amdgcn_mfma_f32_16x16x32_bf16(a0, b0, acc[ob], 0, 0, 0);
            acc[ob] = __builtin_amdgcn_mfma_f32_16x16x32_bf16(a1, b1, acc[ob], 0, 0, 0);
        }
    }
#pragma unroll
    for (int ob = 0; ob < 4; ++ob) {
        int o = ob * 16 + l15;
        float bias = db[o];
        f4v v = acc[ob];
        v.x += bias; v.y += bias; v.z += bias; v.w += bias;
        *(f4v*)&outp[((size_t)(b * kD + o)) * kHW + y * kW + wave * 16 + q * 4] = v;
    }
}

// ---------------------------------------------------------------------------
// Kernel 4: 9-tap local attention on bf16 PIXEL-MAJOR q/k/v.
// Block = 1 row: 256 threads = 64 px x 4 channel-groups (16 ch each).
// Lane = pxq*4 + cg  ->  partial QK over 16 ch, reduced with 2 shfl_xor
// (no LDS, no barrier). Zero-padded taps: score exactly 0, participate in
// softmax; v masked to 0. Output bf16 pixel-major ao[p][192].
// ---------------------------------------------------------------------------
__global__ __launch_bounds__(256) void attn_px(const ushort_t* __restrict__ qpx,
                                               const ushort_t* __restrict__ kpx,
                                               const ushort_t* __restrict__ vpx,
                                               ushort_t* __restrict__ aopx,
                                               int branch, int dil) {
    const int lb = (blockIdx.x & 7) * 64 + (blockIdx.x >> 3);   // XCD swizzle (G=512)
    const int b = lb >> 6;
    const int y = lb & 63;
    const int tid  = threadIdx.x;
    const int wave = tid >> 6;
    const int l    = tid & 63;
    const int pxq  = l >> 2;
    const int cg   = l & 3;
    const int x = wave * 16 + pxq;
    const int p = y * kW + x;
    const size_t pbase = (size_t)b * kHW;

    const ushort_t* qb = qpx + (pbase + p) * 64 + cg * 16;
    s8v q0 = *(const s8v*)qb;
    s8v q1 = *(const s8v*)(qb + 8);
    float qf[16];
#pragma unroll
    for (int j = 0; j < 8; ++j) { qf[j] = bfu(q0[j]); qf[8 + j] = bfu(q1[j]); }

    int offs[9]; float msk[9];
#pragma unroll
    for (int kk = 0; kk < 9; ++kk) {
        int dy = (kk / 3 - 1) * dil, dx = (kk % 3 - 1) * dil;
        int yy = y + dy, xx = x + dx;
        bool v = (yy >= 0) & (yy < kH) & (xx >= 0) & (xx < kW);
        offs[kk] = v ? (p + dy * kW + dx) : p;
        msk[kk] = v ? 1.f : 0.f;
    }
    float e[9];
#pragma unroll
    for (int kk = 0; kk < 9; ++kk) {
        const ushort_t* kp = kpx + (pbase + offs[kk]) * 64 + cg * 16;
        s8v k0 = *(const s8v*)kp;
        s8v k1 = *(const s8v*)(kp + 8);
        float s = 0.f;
#pragma unroll
        for (int j = 0; j < 8; ++j) {
            s += qf[j] * bfu(k0[j]);
            s += qf[8 + j] * bfu(k1[j]);
        }
        s += __shfl_xor(s, 1);
        s += __shfl_xor(s, 2);
        e[kk] = s * 0.125f * msk[kk];
    }
    float mx = -1e30f;
#pragma unroll
    for (int kk = 0; kk < 9; ++kk) mx = fmaxf(mx, e[kk]);
    float ssum = 0.f;
#pragma unroll
    for (int kk = 0; kk < 9; ++kk) { e[kk] = __expf(e[kk] - mx); ssum += e[kk]; }
    float inv = 1.f / ssum;
#pragma unroll
    for (int kk = 0; kk < 9; ++kk) e[kk] = e[kk] * inv * msk[kk];

    float acc[16];
#pragma unroll
    for (int j = 0; j < 16; ++j) acc[j] = 0.f;
#pragma unroll
    for (int kk = 0; kk < 9; ++kk) {
        const ushort_t* vp = vpx + (pbase + offs[kk]) * 64 + cg * 16;
        s8v v0 = *(const s8v*)vp;
        s8v v1 = *(const s8v*)(vp + 8);
        float w = e[kk];
#pragma unroll
        for (int j = 0; j < 8; ++j) {
            acc[j] += w * bfu(v0[j]);
            acc[8 + j] += w * bfu(v1[j]);
        }
    }
    unsigned u[8];
#pragma unroll
    for (int i = 0; i < 8; ++i)
        u[i] = (unsigned)bf16r(acc[2 * i]) | ((unsigned)bf16r(acc[2 * i + 1]) << 16);
    ushort_t* ob = aopx + (pbase + p) * kC + branch * 64 + cg * 16;
    *(uint4*)ob = make_uint4(u[0], u[1], u[2], u[3]);
    *(uint4*)(ob + 8) = make_uint4(u[4], u[5], u[6], u[7]);
}

// ---------------------------------------------------------------------------
// Kernel 5: output projection via bf16 MFMA on pixel-major ao.
// A = proj weight rows (n), B = ao pixel rows; D row = n, col = pixel.
// Store: lane writes 4 consecutive n at its pixel -> 16B contiguous fp32.
// ---------------------------------------------------------------------------
__global__ __launch_bounds__(256) void proj_mfma(const ushort_t* __restrict__ aopx,
                                                 const ushort_t* __restrict__ pwb,
                                                 const float* __restrict__ pb,
                                                 float* __restrict__ out) {
    const int tid  = threadIdx.x;
    const int lane = tid & 63;
    const int wave = tid >> 6;
    const int l15  = lane & 15;
    const int q    = lane >> 4;
    const int m0   = blockIdx.x * 64;
    const int nb   = blockIdx.y * 64 + wave * 16;

    f4v acc[4];
#pragma unroll
    for (int ob = 0; ob < 4; ++ob) acc[ob] = (f4v){0.f, 0.f, 0.f, 0.f};

    const ushort_t* aw = pwb + (size_t)(nb + l15) * kC + q * 8;
    const ushort_t* bx = aopx + (size_t)(m0 + l15) * kC + q * 8;
#pragma unroll
    for (int kc = 0; kc < 6; ++kc) {
        s8v a = *(const s8v*)(aw + kc * 32);
#pragma unroll
        for (int ob = 0; ob < 4; ++ob) {
            s8v b = *(const s8v*)(bx + (size_t)(ob * 16) * kC + kc * 32);
            acc[ob] = __builtin_amdgcn_mfma_f32_16x16x32_bf16(a, b, acc[ob], 0, 0, 0);
        }
    }
    float4 bias = *(const float4*)&pb[nb + q * 4];
#pragma unroll
    for (int ob = 0; ob < 4; ++ob) {
        int m = m0 + ob * 16 + l15;
        f4v v = acc[ob];
        v.x += bias.x; v.y += bias.y; v.z += bias.z; v.w += bias.w;
        *(f4v*)&out[(size_t)m * kC + nb + q * 4] = v;
    }
}

// ---------------------------------------------------------------------------
// Host launcher.  Fresh workspace layout, no aliasing (total ~95 MB, under
// the proven-fitting 120 MB):
//   fp32: offb 18 | kd 64 | vd 64 planes  (plane = kM floats)
//   bf16: xb (M*192) | qkvpx (9*M*64: q0,q1,q2,k0,k1,k2,v0,v1,v2) |
//         kdpx, vdpx (M*64 each) | aopx (M*192) | qwb | pwb | dwtb2/3 | owtb2/3
// ---------------------------------------------------------------------------
extern "C" void kernel_launch(void* const* d_in, const int* in_sizes, int n_in,
                              void* d_out, int out_size, void* d_ws, size_t ws_size,
                              hipStream_t stream) {
    const float* x      = (const float*)d_in[0];
    const float* qkv_w  = (const float*)d_in[1];
    const float* proj_w = (const float*)d_in[2];
    const float* proj_b = (const float*)d_in[3];
    const float* off_w2 = (const float*)d_in[4];
    const float* off_b2 = (const float*)d_in[5];
    const float* def_w2 = (const float*)d_in[6];
    const float* def_b2 = (const float*)d_in[7];
    const float* off_w3 = (const float*)d_in[8];
    const float* off_b3 = (const float*)d_in[9];
    const float* def_w3 = (const float*)d_in[10];
    const float* def_b3 = (const float*)d_in[11];
    float* out = (float*)d_out;

    float* ws   = (float*)d_ws;
    float* offb = ws;                               // 18 * M
    float* kd   = offb + (size_t)18 * kM;           // 64 * M
    float* vd   = kd + (size_t)kD * kM;             // 64 * M
    ushort_t* us = (ushort_t*)(vd + (size_t)kD * kM);
    ushort_t* xb     = us;  us += (size_t)kM * kC;
    ushort_t* qkvpx  = us;  us += (size_t)9 * kM * 64;
    ushort_t* kdpx   = us;  us += (size_t)kM * 64;
    ushort_t* vdpx   = us;  us += (size_t)kM * 64;
    ushort_t* aopx   = us;  us += (size_t)kM * kC;
    ushort_t* qwb    = us;  us += (size_t)kNQKV * kC;
    ushort_t* pwb    = us;  us += (size_t)kC * kC;
    ushort_t* dwtb2  = us;  us += kD * kD * 9;
    ushort_t* dwtb3  = us;  us += kD * kD * 9;
    ushort_t* owtb2  = us;  us += 9 * 32 * 64;
    ushort_t* owtb3  = us;  us += 9 * 32 * 64;

    // 0. bf16 conversions and weight transposes
    cvt_bf16<<<(kM * kC / 2 + 255) / 256, 256, 0, stream>>>(x, (unsigned*)xb, kM * kC / 2);
    cvt_bf16<<<(kNQKV * kC / 2 + 255) / 256, 256, 0, stream>>>(qkv_w, (unsigned*)qwb, kNQKV * kC / 2);
    cvt_bf16<<<(kC * kC / 2 + 255) / 256, 256, 0, stream>>>(proj_w, (unsigned*)pwb, kC * kC / 2);
    dw_tb<<<144, 256, 0, stream>>>(def_w2, dwtb2);
    dw_tb<<<144, 256, 0, stream>>>(def_w3, dwtb3);
    ow_tb<<<72, 256, 0, stream>>>(off_w2, owtb2);
    ow_tb<<<72, 256, 0, stream>>>(off_w3, owtb3);

    // per-tensor pixel-major slices
    ushort_t* q0 = qkvpx;
    ushort_t* q1 = qkvpx + (size_t)1 * kM * 64;
    ushort_t* q2 = qkvpx + (size_t)2 * kM * 64;
    ushort_t* k0 = qkvpx + (size_t)3 * kM * 64;
    ushort_t* k1 = qkvpx + (size_t)4 * kM * 64;
    ushort_t* k2 = qkvpx + (size_t)5 * kM * 64;
    ushort_t* v0 = qkvpx + (size_t)6 * kM * 64;
    ushort_t* v1 = qkvpx + (size_t)7 * kM * 64;
    ushort_t* v2 = qkvpx + (size_t)8 * kM * 64;

    // 1. QKV projection -> 9 bf16 pixel-major tensors
    qkv_mfma2<<<dim3(kM / 64, 9), 256, 0, stream>>>(xb, qwb, qkvpx);

    // 2. branch 0 (dil=1)
    attn_px<<<kB * kH, 256, 0, stream>>>(q0, k0, v0, aopx, 0, 1);

    // 3. branch 1 (dil=2)
    off_conv_mfma<<<512, 256, 0, stream>>>(k1, owtb2, off_b2, offb, 2);
    deform_mfma<<<1024, 256, 0, stream>>>(k1, v1, offb, dwtb2, def_b2, kd, vd, 2);
    repack_px<<<256, 256, 0, stream>>>(kd, vd, kdpx, vdpx, kD * kHW);
    attn_px<<<kB * kH, 256, 0, stream>>>(q1, kdpx, vdpx, aopx, 1, 2);

    // 4. branch 2 (dil=3)
    off_conv_mfma<<<512, 256, 0, stream>>>(k2, owtb3, off_b3, offb, 3);
    deform_mfma<<<1024, 256, 0, stream>>>(k2, v2, offb, dwtb3, def_b3, kd, vd, 3);
    repack_px<<<256, 256, 0, stream>>>(kd, vd, kdpx, vdpx, kD * kHW);
    attn_px<<<kB * kH, 256, 0, stream>>>(q2, kdpx, vdpx, aopx, 2, 3);

    // 5. output projection (bf16 MFMA, fp32 out)
    proj_mfma<<<dim3(kM / 64, 3), 256, 0, stream>>>(aopx, pwb, proj_b, out);
}

// Round 10
// 374.377 us; speedup vs baseline: 2.9698x; 1.0406x over previous
//
#include <hip/hip_runtime.h>
#include <cmath>

// ---------------------------------------------------------------------------
// Problem constants (B=8, H=W=64, C=192, 3 dilation branches of d=64, heads=64)
// ---------------------------------------------------------------------------
#define kB    8
#define kH    64
#define kW    64
#define kHW   4096          // H*W
#define kC    192
#define kD    64            // channels per dilation branch == head_dim
#define kM    (kB * kHW)    // 32768 total pixels
#define kNQKV 576           // 3*C

typedef unsigned short ushort_t;
typedef __attribute__((ext_vector_type(8))) short  s8v;   // 8 bf16 (4 VGPRs)
typedef __attribute__((ext_vector_type(4))) float  f4v;   // MFMA C/D frag

__device__ inline unsigned short bf16r(float f) {   // round-to-nearest-even
    union { float f; unsigned u; } v; v.f = f;
    unsigned u = v.u + 0x7FFFu + ((v.u >> 16) & 1u);
    return (unsigned short)(u >> 16);
}
__device__ inline float bfu(short s) {              // bf16 -> fp32
    union { unsigned u; float f; } v;
    v.u = ((unsigned)(unsigned short)s) << 16;
    return v.f;
}

// ---------------------------------------------------------------------------
// fp32 -> bf16 pairwise converter
// ---------------------------------------------------------------------------
__global__ void cvt_bf16(const float* __restrict__ src, unsigned* __restrict__ dst, int n2) {
    int i = blockIdx.x * 256 + threadIdx.x;
    if (i >= n2) return;
    float2 f = ((const float2*)src)[i];
    dst[i] = (unsigned)bf16r(f.x) | ((unsigned)bf16r(f.y) << 16);
}

// ---------------------------------------------------------------------------
// deform weights: dw (o,c,kk) fp32 -> dwtb[kk][o][c] bf16
// ---------------------------------------------------------------------------
__global__ void dw_tb(const float* __restrict__ dw, ushort_t* __restrict__ dwtb) {
    int l = blockIdx.x * 256 + threadIdx.x;   // 64*64*9 = 36864
    if (l >= kD * kD * 9) return;
    int o = l / 576;
    int c = (l / 9) % 64;
    int kk = l % 9;
    dwtb[(kk * 64 + o) * 64 + c] = bf16r(dw[l]);
}

// ---------------------------------------------------------------------------
// offset-conv weights: ow (18,64,3,3) fp32 -> owtb[kk][n=32 pad][c=64] bf16
// ---------------------------------------------------------------------------
__global__ void ow_tb(const float* __restrict__ ow, ushort_t* __restrict__ owtb) {
    int l = blockIdx.x * 256 + threadIdx.x;   // 9*32*64 = 18432
    if (l >= 9 * 32 * 64) return;
    int kk = l >> 11;
    int j  = (l >> 6) & 31;
    int c  = l & 63;
    owtb[l] = (j < 18) ? bf16r(ow[j * 576 + c * 9 + kk]) : (ushort_t)0;
}

// ---------------------------------------------------------------------------
// Kernel 1: QKV projection, MFMA, output bf16 PIXEL-MAJOR per tensor.
// A = weight rows (channel), B = pixel rows; D row = channel, col = pixel.
// blockIdx.y = tensor 0..8 (q0,q1,q2,k0,k1,k2,v0,v1,v2), each [b][p][64] bf16.
// ---------------------------------------------------------------------------
__global__ __launch_bounds__(256) void qkv_mfma2(const ushort_t* __restrict__ xb,
                                                 const ushort_t* __restrict__ qwb,
                                                 ushort_t* __restrict__ qkvpx) {
    const int tid  = threadIdx.x;
    const int lane = tid & 63;
    const int wave = tid >> 6;
    const int l15  = lane & 15;
    const int q    = lane >> 4;
    const int m0   = blockIdx.x * 64;
    const int ty   = blockIdx.y;                 // tensor index
    const int nb   = ty * 64 + wave * 16;        // global qkv channel strip

    f4v acc[4];
#pragma unroll
    for (int ob = 0; ob < 4; ++ob) acc[ob] = (f4v){0.f, 0.f, 0.f, 0.f};

    const ushort_t* aw = qwb + (size_t)(nb + l15) * kC + q * 8;   // A: weight rows
    const ushort_t* bx = xb + (size_t)(m0 + l15) * kC + q * 8;    // B: pixel rows
#pragma unroll
    for (int kc = 0; kc < 6; ++kc) {
        s8v a = *(const s8v*)(aw + kc * 32);
#pragma unroll
        for (int ob = 0; ob < 4; ++ob) {
            s8v b = *(const s8v*)(bx + (size_t)(ob * 16) * kC + kc * 32);
            acc[ob] = __builtin_amdgcn_mfma_f32_16x16x32_bf16(a, b, acc[ob], 0, 0, 0);
        }
    }
    ushort_t* obase = qkvpx + (size_t)ty * kM * 64 + (size_t)m0 * 64 + wave * 16 + q * 4;
#pragma unroll
    for (int ob = 0; ob < 4; ++ob) {
        f4v v = acc[ob];
        uint2 u;
        u.x = (unsigned)bf16r(v.x) | ((unsigned)bf16r(v.y) << 16);
        u.y = (unsigned)bf16r(v.z) | ((unsigned)bf16r(v.w) << 16);
        *(uint2*)(obase + (size_t)(ob * 16 + l15) * 64) = u;
    }
}

// ---------------------------------------------------------------------------
// Kernel 2: offsets conv via bf16 MFMA over pixel-major k.
// ---------------------------------------------------------------------------
__global__ __launch_bounds__(256) void off_conv_mfma(const ushort_t* __restrict__ kpx,
                                                     const ushort_t* __restrict__ owtb,
                                                     const float* __restrict__ obias,
                                                     float* __restrict__ offb,
                                                     int dil) {
    const int lb = (blockIdx.x & 7) * 64 + (blockIdx.x >> 3);   // XCD swizzle (G=512)
    const int b = lb >> 6;
    const int y = lb & 63;
    const int tid  = threadIdx.x;
    const int lane = tid & 63;
    const int wave = tid >> 6;
    const int l15  = lane & 15;
    const int q    = lane >> 4;
    const int px   = wave * 16 + l15;

    const ushort_t* inpx = kpx + (size_t)b * kHW * 64 + q * 8;

    f4v acc[2];
    acc[0] = (f4v){0.f, 0.f, 0.f, 0.f};
    acc[1] = (f4v){0.f, 0.f, 0.f, 0.f};

#pragma unroll
    for (int kk = 0; kk < 9; ++kk) {
        const int yy = y + (kk / 3 - 1) * dil;
        const int xx = px + (kk % 3 - 1) * dil;
        const bool valid = (yy >= 0) & (yy < kH) & (xx >= 0) & (xx < kW);
        const size_t idx = valid ? (size_t)(yy * kW + xx) * 64 : 0;
        s8v a0 = *(const s8v*)(inpx + idx);
        s8v a1 = *(const s8v*)(inpx + idx + 32);
        if (!valid) {
            a0 = (s8v){0, 0, 0, 0, 0, 0, 0, 0};
            a1 = (s8v){0, 0, 0, 0, 0, 0, 0, 0};
        }
        const ushort_t* wb = owtb + (size_t)kk * 2048 + l15 * 64 + q * 8;
#pragma unroll
        for (int nbk = 0; nbk < 2; ++nbk) {
            s8v b0 = *(const s8v*)(wb + nbk * 1024);
            s8v b1 = *(const s8v*)(wb + nbk * 1024 + 32);
            acc[nbk] = __builtin_amdgcn_mfma_f32_16x16x32_bf16(a0, b0, acc[nbk], 0, 0, 0);
            acc[nbk] = __builtin_amdgcn_mfma_f32_16x16x32_bf16(a1, b1, acc[nbk], 0, 0, 0);
        }
    }
#pragma unroll
    for (int nbk = 0; nbk < 2; ++nbk) {
        int n = nbk * 16 + l15;
        if (n < 18) {
            float bias = obias[n];
            f4v v = acc[nbk];
            v.x += bias; v.y += bias; v.z += bias; v.w += bias;
            *(f4v*)&offb[((size_t)b * 18 + n) * kHW + y * kW + wave * 16 + q * 4] = v;
        }
    }
}

// ---------------------------------------------------------------------------
// Kernel 3: deformable 3x3 conv via bf16 MFMA, pixel-major in AND out.
// Round-10 rewrite of the latency-bound version (VALUBusy 18%, MfmaUtil 2.6%,
// occupancy 40% — everything idle waiting on the per-tap gather chain):
//  (a) operand-role swap: A = dwtb weights (m=o), B = sampled pixels (n=px)
//      -> D row=o, col=pixel -> lane stores 4 consecutive channels at its
//      pixel = direct bf16 pixel-major output (kills the 16 MB fp32 planar
//      write and the repack_px pass entirely).
//  (b) all 18 offsets prefetched to registers before the tap loop.
//  (c) manual 2-deep pipeline: tap k+1's 8 corner gathers issue before tap
//      k's bilinear+MFMA, fully unrolled.
// ---------------------------------------------------------------------------
__global__ __launch_bounds__(256) void deform_mfma(const ushort_t* __restrict__ kpx,
                                                   const ushort_t* __restrict__ vpx,
                                                   const float* __restrict__ offb,
                                                   const ushort_t* __restrict__ dwtb,
                                                   const float* __restrict__ db,
                                                   ushort_t* __restrict__ outkpx,
                                                   ushort_t* __restrict__ outvpx,
                                                   int dil) {
    const int lb = (blockIdx.x & 7) * 128 + (blockIdx.x >> 3);  // XCD swizzle (G=1024)
    const int t = lb >> 9;          // 0 = k, 1 = v
    const int b = (lb >> 6) & 7;
    const int y = lb & 63;
    const int tid  = threadIdx.x;
    const int lane = tid & 63;
    const int wave = tid >> 6;
    const int l15  = lane & 15;
    const int q    = lane >> 4;
    const int px   = wave * 16 + l15;   // B-operand pixel for this lane

    const ushort_t* inpx = (t ? vpx : kpx) + (size_t)b * kHW * 64 + q * 8;
    ushort_t* outp = t ? outvpx : outkpx;

    f4v acc[4];
#pragma unroll
    for (int ob = 0; ob < 4; ++ob) acc[ob] = (f4v){0.f, 0.f, 0.f, 0.f};

    // prefetch all 18 offset channels for my pixel
    const float* offrow = offb + (size_t)b * 18 * kHW + y * kW + px;
    float offv[18];
#pragma unroll
    for (int i = 0; i < 18; ++i) offv[i] = offrow[(size_t)i * kHW];

    auto sample_tap = [&](int kk, s8v* c, float* w) {
        float oy = offv[kk * 2 + 0];
        float ox = offv[kk * 2 + 1];
        float py  = (float)y  + (float)((kk / 3 - 1) * dil) + oy;
        float pxf = (float)px + (float)((kk % 3 - 1) * dil) + ox;
        float fy = floorf(py), fx = floorf(pxf);
        float wy = py - fy, wx = pxf - fx;
        int y0 = (int)fy, x0 = (int)fx;
        int y1 = y0 + 1, x1 = x0 + 1;
        int y0c = min(max(y0, 0), kH - 1), x0c = min(max(x0, 0), kW - 1);
        int y1c = min(max(y1, 0), kH - 1), x1c = min(max(x1, 0), kW - 1);
        bool vy0 = (y0 >= 0) & (y0 < kH), vx0 = (x0 >= 0) & (x0 < kW);
        bool vy1 = (y1 >= 0) & (y1 < kH), vx1 = (x1 >= 0) & (x1 < kW);
        size_t i00 = (size_t)(y0c * kW + x0c) * 64;
        size_t i01 = (size_t)(y0c * kW + x1c) * 64;
        size_t i10 = (size_t)(y1c * kW + x0c) * 64;
        size_t i11 = (size_t)(y1c * kW + x1c) * 64;
        w[0] = (vy0 && vx0) ? (1.f - wy) * (1.f - wx) : 0.f;
        w[1] = (vy0 && vx1) ? (1.f - wy) * wx : 0.f;
        w[2] = (vy1 && vx0) ? wy * (1.f - wx) : 0.f;
        w[3] = (vy1 && vx1) ? wy * wx : 0.f;
        c[0] = *(const s8v*)(inpx + i00);
        c[1] = *(const s8v*)(inpx + i00 + 32);
        c[2] = *(const s8v*)(inpx + i01);
        c[3] = *(const s8v*)(inpx + i01 + 32);
        c[4] = *(const s8v*)(inpx + i10);
        c[5] = *(const s8v*)(inpx + i10 + 32);
        c[6] = *(const s8v*)(inpx + i11);
        c[7] = *(const s8v*)(inpx + i11 + 32);
    };

    s8v cur[8], nxt[8];
    float wcur[4], wnxt[4];
    sample_tap(0, cur, wcur);
#pragma unroll
    for (int kk = 0; kk < 9; ++kk) {
        if (kk < 8) sample_tap(kk + 1, nxt, wnxt);   // prefetch next tap
        // bilinear for current tap -> two B-frags (channel chunks)
        s8v b0, b1;
#pragma unroll
        for (int j = 0; j < 8; ++j) {
            float v0 = wcur[0] * bfu(cur[0][j]) + wcur[1] * bfu(cur[2][j]) +
                       wcur[2] * bfu(cur[4][j]) + wcur[3] * bfu(cur[6][j]);
            float v1 = wcur[0] * bfu(cur[1][j]) + wcur[1] * bfu(cur[3][j]) +
                       wcur[2] * bfu(cur[5][j]) + wcur[3] * bfu(cur[7][j]);
            b0[j] = (short)bf16r(v0);
            b1[j] = (short)bf16r(v1);
        }
        // A-frags: dwtb[kk][o = obb*16+l15][c = q*8 (+32)]
        const ushort_t* wb = dwtb + (size_t)kk * 4096 + l15 * 64 + q * 8;
#pragma unroll
        for (int obb = 0; obb < 4; ++obb) {
            s8v a0w = *(const s8v*)(wb + obb * 1024);
            s8v a1w = *(const s8v*)(wb + obb * 1024 + 32);
            acc[obb] = __builtin_amdgcn_mfma_f32_16x16x32_bf16(a0w, b0, acc[obb], 0, 0, 0);
            acc[obb] = __builtin_amdgcn_mfma_f32_16x16x32_bf16(a1w, b1, acc[obb], 0, 0, 0);
        }
        if (kk < 8) {
#pragma unroll
            for (int i = 0; i < 8; ++i) cur[i] = nxt[i];
#pragma unroll
            for (int i = 0; i < 4; ++i) wcur[i] = wnxt[i];
        }
    }
    // store: lane holds o = obb*16 + q*4 + reg at pixel px -> bf16 pixel-major
    ushort_t* orow = outp + ((size_t)b * kHW + y * kW + px) * 64 + q * 4;
#pragma unroll
    for (int obb = 0; obb < 4; ++obb) {
        float4 bias = *(const float4*)&db[obb * 16 + q * 4];
        f4v v = acc[obb];
        uint2 u;
        u.x = (unsigned)bf16r(v.x + bias.x) | ((unsigned)bf16r(v.y + bias.y) << 16);
        u.y = (unsigned)bf16r(v.z + bias.z) | ((unsigned)bf16r(v.w + bias.w) << 16);
        *(uint2*)(orow + obb * 16) = u;
    }
}

// ---------------------------------------------------------------------------
// Kernel 4: 9-tap local attention on bf16 PIXEL-MAJOR q/k/v.
// Block = 1 row: 256 threads = 64 px x 4 channel-groups (16 ch each).
// ---------------------------------------------------------------------------
__global__ __launch_bounds__(256) void attn_px(const ushort_t* __restrict__ qpx,
                                               const ushort_t* __restrict__ kpx,
                                               const ushort_t* __restrict__ vpx,
                                               ushort_t* __restrict__ aopx,
                                               int branch, int dil) {
    const int lb = (blockIdx.x & 7) * 64 + (blockIdx.x >> 3);   // XCD swizzle (G=512)
    const int b = lb >> 6;
    const int y = lb & 63;
    const int tid  = threadIdx.x;
    const int wave = tid >> 6;
    const int l    = tid & 63;
    const int pxq  = l >> 2;
    const int cg   = l & 3;
    const int x = wave * 16 + pxq;
    const int p = y * kW + x;
    const size_t pbase = (size_t)b * kHW;

    const ushort_t* qb = qpx + (pbase + p) * 64 + cg * 16;
    s8v q0 = *(const s8v*)qb;
    s8v q1 = *(const s8v*)(qb + 8);
    float qf[16];
#pragma unroll
    for (int j = 0; j < 8; ++j) { qf[j] = bfu(q0[j]); qf[8 + j] = bfu(q1[j]); }

    int offs[9]; float msk[9];
#pragma unroll
    for (int kk = 0; kk < 9; ++kk) {
        int dy = (kk / 3 - 1) * dil, dx = (kk % 3 - 1) * dil;
        int yy = y + dy, xx = x + dx;
        bool v = (yy >= 0) & (yy < kH) & (xx >= 0) & (xx < kW);
        offs[kk] = v ? (p + dy * kW + dx) : p;
        msk[kk] = v ? 1.f : 0.f;
    }
    float e[9];
#pragma unroll
    for (int kk = 0; kk < 9; ++kk) {
        const ushort_t* kp = kpx + (pbase + offs[kk]) * 64 + cg * 16;
        s8v k0 = *(const s8v*)kp;
        s8v k1 = *(const s8v*)(kp + 8);
        float s = 0.f;
#pragma unroll
        for (int j = 0; j < 8; ++j) {
            s += qf[j] * bfu(k0[j]);
            s += qf[8 + j] * bfu(k1[j]);
        }
        s += __shfl_xor(s, 1);
        s += __shfl_xor(s, 2);
        e[kk] = s * 0.125f * msk[kk];
    }
    float mx = -1e30f;
#pragma unroll
    for (int kk = 0; kk < 9; ++kk) mx = fmaxf(mx, e[kk]);
    float ssum = 0.f;
#pragma unroll
    for (int kk = 0; kk < 9; ++kk) { e[kk] = __expf(e[kk] - mx); ssum += e[kk]; }
    float inv = 1.f / ssum;
#pragma unroll
    for (int kk = 0; kk < 9; ++kk) e[kk] = e[kk] * inv * msk[kk];

    float acc[16];
#pragma unroll
    for (int j = 0; j < 16; ++j) acc[j] = 0.f;
#pragma unroll
    for (int kk = 0; kk < 9; ++kk) {
        const ushort_t* vp = vpx + (pbase + offs[kk]) * 64 + cg * 16;
        s8v v0 = *(const s8v*)vp;
        s8v v1 = *(const s8v*)(vp + 8);
        float w = e[kk];
#pragma unroll
        for (int j = 0; j < 8; ++j) {
            acc[j] += w * bfu(v0[j]);
            acc[8 + j] += w * bfu(v1[j]);
        }
    }
    unsigned u[8];
#pragma unroll
    for (int i = 0; i < 8; ++i)
        u[i] = (unsigned)bf16r(acc[2 * i]) | ((unsigned)bf16r(acc[2 * i + 1]) << 16);
    ushort_t* ob = aopx + (pbase + p) * kC + branch * 64 + cg * 16;
    *(uint4*)ob = make_uint4(u[0], u[1], u[2], u[3]);
    *(uint4*)(ob + 8) = make_uint4(u[4], u[5], u[6], u[7]);
}

// ---------------------------------------------------------------------------
// Kernel 5: output projection via bf16 MFMA on pixel-major ao.
// ---------------------------------------------------------------------------
__global__ __launch_bounds__(256) void proj_mfma(const ushort_t* __restrict__ aopx,
                                                 const ushort_t* __restrict__ pwb,
                                                 const float* __restrict__ pb,
                                                 float* __restrict__ out) {
    const int tid  = threadIdx.x;
    const int lane = tid & 63;
    const int wave = tid >> 6;
    const int l15  = lane & 15;
    const int q    = lane >> 4;
    const int m0   = blockIdx.x * 64;
    const int nb   = blockIdx.y * 64 + wave * 16;

    f4v acc[4];
#pragma unroll
    for (int ob = 0; ob < 4; ++ob) acc[ob] = (f4v){0.f, 0.f, 0.f, 0.f};

    const ushort_t* aw = pwb + (size_t)(nb + l15) * kC + q * 8;
    const ushort_t* bx = aopx + (size_t)(m0 + l15) * kC + q * 8;
#pragma unroll
    for (int kc = 0; kc < 6; ++kc) {
        s8v a = *(const s8v*)(aw + kc * 32);
#pragma unroll
        for (int ob = 0; ob < 4; ++ob) {
            s8v b = *(const s8v*)(bx + (size_t)(ob * 16) * kC + kc * 32);
            acc[ob] = __builtin_amdgcn_mfma_f32_16x16x32_bf16(a, b, acc[ob], 0, 0, 0);
        }
    }
    float4 bias = *(const float4*)&pb[nb + q * 4];
#pragma unroll
    for (int ob = 0; ob < 4; ++ob) {
        int m = m0 + ob * 16 + l15;
        f4v v = acc[ob];
        v.x += bias.x; v.y += bias.y; v.z += bias.z; v.w += bias.w;
        *(f4v*)&out[(size_t)m * kC + nb + q * 4] = v;
    }
}

// ---------------------------------------------------------------------------
// Host launcher.  Workspace (~63 MB, well under the proven 120 MB):
//   fp32: offb 18 planes
//   bf16: xb (M*192) | qkvpx (9*M*64) | kdpx, vdpx (M*64) | aopx (M*192) |
//         qwb | pwb | dwtb2/3 | owtb2/3
// (kd/vd fp32 planes and repack_px are gone — deform writes bf16 px-major.)
// ---------------------------------------------------------------------------
extern "C" void kernel_launch(void* const* d_in, const int* in_sizes, int n_in,
                              void* d_out, int out_size, void* d_ws, size_t ws_size,
                              hipStream_t stream) {
    const float* x      = (const float*)d_in[0];
    const float* qkv_w  = (const float*)d_in[1];
    const float* proj_w = (const float*)d_in[2];
    const float* proj_b = (const float*)d_in[3];
    const float* off_w2 = (const float*)d_in[4];
    const float* off_b2 = (const float*)d_in[5];
    const float* def_w2 = (const float*)d_in[6];
    const float* def_b2 = (const float*)d_in[7];
    const float* off_w3 = (const float*)d_in[8];
    const float* off_b3 = (const float*)d_in[9];
    const float* def_w3 = (const float*)d_in[10];
    const float* def_b3 = (const float*)d_in[11];
    float* out = (float*)d_out;

    float* ws   = (float*)d_ws;
    float* offb = ws;                               // 18 * M
    ushort_t* us = (ushort_t*)(offb + (size_t)18 * kM);
    ushort_t* xb     = us;  us += (size_t)kM * kC;
    ushort_t* qkvpx  = us;  us += (size_t)9 * kM * 64;
    ushort_t* kdpx   = us;  us += (size_t)kM * 64;
    ushort_t* vdpx   = us;  us += (size_t)kM * 64;
    ushort_t* aopx   = us;  us += (size_t)kM * kC;
    ushort_t* qwb    = us;  us += (size_t)kNQKV * kC;
    ushort_t* pwb    = us;  us += (size_t)kC * kC;
    ushort_t* dwtb2  = us;  us += kD * kD * 9;
    ushort_t* dwtb3  = us;  us += kD * kD * 9;
    ushort_t* owtb2  = us;  us += 9 * 32 * 64;
    ushort_t* owtb3  = us;  us += 9 * 32 * 64;

    // 0. bf16 conversions and weight transposes
    cvt_bf16<<<(kM * kC / 2 + 255) / 256, 256, 0, stream>>>(x, (unsigned*)xb, kM * kC / 2);
    cvt_bf16<<<(kNQKV * kC / 2 + 255) / 256, 256, 0, stream>>>(qkv_w, (unsigned*)qwb, kNQKV * kC / 2);
    cvt_bf16<<<(kC * kC / 2 + 255) / 256, 256, 0, stream>>>(proj_w, (unsigned*)pwb, kC * kC / 2);
    dw_tb<<<144, 256, 0, stream>>>(def_w2, dwtb2);
    dw_tb<<<144, 256, 0, stream>>>(def_w3, dwtb3);
    ow_tb<<<72, 256, 0, stream>>>(off_w2, owtb2);
    ow_tb<<<72, 256, 0, stream>>>(off_w3, owtb3);

    // per-tensor pixel-major slices
    ushort_t* q0 = qkvpx;
    ushort_t* q1 = qkvpx + (size_t)1 * kM * 64;
    ushort_t* q2 = qkvpx + (size_t)2 * kM * 64;
    ushort_t* k0 = qkvpx + (size_t)3 * kM * 64;
    ushort_t* k1 = qkvpx + (size_t)4 * kM * 64;
    ushort_t* k2 = qkvpx + (size_t)5 * kM * 64;
    ushort_t* v0 = qkvpx + (size_t)6 * kM * 64;
    ushort_t* v1 = qkvpx + (size_t)7 * kM * 64;
    ushort_t* v2 = qkvpx + (size_t)8 * kM * 64;

    // 1. QKV projection -> 9 bf16 pixel-major tensors
    qkv_mfma2<<<dim3(kM / 64, 9), 256, 0, stream>>>(xb, qwb, qkvpx);

    // 2. branch 0 (dil=1)
    attn_px<<<kB * kH, 256, 0, stream>>>(q0, k0, v0, aopx, 0, 1);

    // 3. branch 1 (dil=2)
    off_conv_mfma<<<512, 256, 0, stream>>>(k1, owtb2, off_b2, offb, 2);
    deform_mfma<<<1024, 256, 0, stream>>>(k1, v1, offb, dwtb2, def_b2, kdpx, vdpx, 2);
    attn_px<<<kB * kH, 256, 0, stream>>>(q1, kdpx, vdpx, aopx, 1, 2);

    // 4. branch 2 (dil=3)
    off_conv_mfma<<<512, 256, 0, stream>>>(k2, owtb3, off_b3, offb, 3);
    deform_mfma<<<1024, 256, 0, stream>>>(k2, v2, offb, dwtb3, def_b3, kdpx, vdpx, 3);
    attn_px<<<kB * kH, 256, 0, stream>>>(q2, kdpx, vdpx, aopx, 2, 3);

    // 5. output projection (bf16 MFMA, fp32 out)
    proj_mfma<<<dim3(kM / 64, 3), 256, 0, stream>>>(aopx, pwb, proj_b, out);
}